// Round 5
// baseline (1625.038 us; speedup 1.0000x reference)
//
#include <hip/hip_runtime.h>

#define NPIX 250000
#define NSUP 50000
#define NE   800000
#define DD   128
#define NL   5

#define BN_EPS_C 1e-5f
#define SLOPE 0.01f
#define INV_C (1.0f / 2.9f)

// feature chunking for L2-resident SpMM operand
#define NCH   4
#define CW    32                      // channels per chunk
#define CHSZ  ((size_t)NSUP * CW)     // elems per chunk (bf16): 3.2 MB

// edge capacity with per-row pad to multiple of 4
#define NEPAD4 (NE + 3 * NSUP)
// scan geometry: 1024 threads x 52 elements, covers 53248 >= NSUP
#define SCAN_PER 52
#define CNT_CAP (1024 * SCAN_PER)

__device__ __forceinline__ size_t rowoff(int r) { return (size_t)r * DD; }

// round-to-nearest-even f32 -> bf16 bits
__device__ __forceinline__ unsigned short f2bf(float f) {
    unsigned int u = __float_as_uint(f);
    unsigned int r = (u + 0x7FFFu + ((u >> 16) & 1u)) >> 16;
    return (unsigned short)r;
}
__device__ __forceinline__ float bf2f_lo(unsigned int v) { return __uint_as_float(v << 16); }
__device__ __forceinline__ float bf2f_hi(unsigned int v) { return __uint_as_float(v & 0xFFFF0000u); }
__device__ __forceinline__ float lrelu(float o) { return o > 0.f ? o : SLOPE * o; }

// ---------------- generic histogram ----------------
__global__ __launch_bounds__(256) void hist_k(const int* __restrict__ ids,
        int* __restrict__ cnt, int n) {
    int e = blockIdx.x * 256 + threadIdx.x;
    if (e >= n) return;
    atomicAdd(cnt + ids[e], 1);
}

// ---------------- single-block scan over padded counters ----------------
template <int PAD>
__global__ __launch_bounds__(1024) void scan_rowptr(const int* __restrict__ cnt,
        int* __restrict__ rp) {
    const int t = threadIdx.x;
    const int lo = t * SCAN_PER;
    int4 c[SCAN_PER / 4];
    int s = 0;
    #pragma unroll
    for (int k = 0; k < SCAN_PER / 4; ++k) {
        int4 v = *(const int4*)(cnt + lo + k * 4);
        if (PAD > 1) {
            v.x = (v.x + PAD - 1) & ~(PAD - 1);
            v.y = (v.y + PAD - 1) & ~(PAD - 1);
            v.z = (v.z + PAD - 1) & ~(PAD - 1);
            v.w = (v.w + PAD - 1) & ~(PAD - 1);
        }
        c[k] = v;
        s += v.x + v.y + v.z + v.w;
    }
    int lane = t & 63, wid = t >> 6;
    int v = s;
    #pragma unroll
    for (int d = 1; d < 64; d <<= 1) {
        int u = __shfl_up(v, d);
        if (lane >= d) v += u;
    }
    __shared__ int wtot[16], woff[16];
    if (lane == 63) wtot[wid] = v;
    __syncthreads();
    if (t == 0) {
        int acc = 0;
        #pragma unroll
        for (int w = 0; w < 16; ++w) { woff[w] = acc; acc += wtot[w]; }
    }
    __syncthreads();
    int base = woff[wid] + v - s;
    #pragma unroll
    for (int k = 0; k < SCAN_PER / 4; ++k) {
        int i = lo + k * 4;
        if (i     <= NSUP) rp[i]     = base;  base += c[k].x;
        if (i + 1 <= NSUP) rp[i + 1] = base;  base += c[k].y;
        if (i + 2 <= NSUP) rp[i + 2] = base;  base += c[k].z;
        if (i + 3 <= NSUP) rp[i + 3] = base;  base += c[k].w;
    }
}

// ---------------- pixel scatter ----------------
__global__ __launch_bounds__(256) void pix_scatter(const int* __restrict__ seg,
        const int* __restrict__ rp, int* __restrict__ fill, int* __restrict__ pix) {
    int p = blockIdx.x * 256 + threadIdx.x;
    if (p >= NPIX) return;
    int s = seg[p];
    int pos = rp[s] + atomicAdd(fill + s, 1);
    pix[pos] = p;
}

// ---------------- edge scatter: interleaved (src, w) pairs ----------------
__global__ __launch_bounds__(256) void edge_scatter(const int* __restrict__ srcv,
        const int* __restrict__ dstv, const float* __restrict__ w,
        const int* __restrict__ rp, int* __restrict__ fill, int2* __restrict__ epk) {
    int e = blockIdx.x * 256 + threadIdx.x;
    if (e >= NE) return;
    int d = dstv[e];
    int pos = rp[d] + atomicAdd(fill + d, 1);
    epk[pos] = make_int2(srcv[e], __float_as_int(w[e]));
}

// ---------------- pooling: half-wave per superpixel, float4 lanes, 2-pixel unroll ----------------
__global__ __launch_bounds__(256) void pool_gather(const float* __restrict__ x,
        const int* __restrict__ pp, const int* __restrict__ pix, float* __restrict__ h) {
    const int tid = threadIdx.x;
    const int wave = tid >> 6, lane = tid & 63;
    const int hf = lane >> 5, hl = lane & 31;
    const int row = blockIdx.x * 8 + wave * 2 + hf;
    const int j0 = pp[row], j1 = pp[row + 1];
    float4 a0 = make_float4(0.f, 0.f, 0.f, 0.f);
    float4 a1 = make_float4(0.f, 0.f, 0.f, 0.f);
    int j = j0;
    for (; j + 1 < j1; j += 2) {
        int p0 = pix[j], p1 = pix[j + 1];
        float4 v0 = *(const float4*)(x + rowoff(p0) + hl * 4);
        float4 v1 = *(const float4*)(x + rowoff(p1) + hl * 4);
        a0.x += v0.x; a0.y += v0.y; a0.z += v0.z; a0.w += v0.w;
        a1.x += v1.x; a1.y += v1.y; a1.z += v1.z; a1.w += v1.w;
    }
    if (j < j1) {
        int p0 = pix[j];
        float4 v0 = *(const float4*)(x + rowoff(p0) + hl * 4);
        a0.x += v0.x; a0.y += v0.y; a0.z += v0.z; a0.w += v0.w;
    }
    float inv = 1.0f / fmaxf((float)(j1 - j0), 1.0f);
    float4 o = make_float4((a0.x + a1.x) * inv, (a0.y + a1.y) * inv,
                           (a0.z + a1.z) * inv, (a0.w + a1.w) * inv);
    *(float4*)(h + rowoff(row) + hl * 4) = o;
}

// ---------------- GEMM: z = act(hin) @ W + b ; y0 = bf16(act(hin) + z) ----------------
// z, y0 written in CHUNKED layout [NCH][NSUP][CW].
// FUSE=1: act(v) = leaky(v*sc + sh)  (BN of previous layer applied on load)
template <int FUSE>
__global__ __launch_bounds__(256) void gemm_bias(const float* __restrict__ hin,
        const float* __restrict__ scsh, const float* __restrict__ W,
        const float* __restrict__ bias,
        unsigned short* __restrict__ zb, unsigned short* __restrict__ y0) {
    __shared__ float hs[32 * DD];   // 16 KB
    __shared__ float Ws[64 * DD];   // 32 KB
    const int tid = threadIdx.x;
    const int r0 = blockIdx.x * 32;
    {
        for (int i = tid; i < 32 * DD / 4; i += 256) {
            int row = i >> 5;
            float4 v = make_float4(0.f, 0.f, 0.f, 0.f);
            if (r0 + row < NSUP) v = *(const float4*)(hin + rowoff(r0 + row) + (i & 31) * 4);
            if (FUSE) {
                float4 scv = *(const float4*)(scsh + (i & 31) * 4);
                float4 shv = *(const float4*)(scsh + 128 + (i & 31) * 4);
                v.x = lrelu(fmaf(v.x, scv.x, shv.x));
                v.y = lrelu(fmaf(v.y, scv.y, shv.y));
                v.z = lrelu(fmaf(v.z, scv.z, shv.z));
                v.w = lrelu(fmaf(v.w, scv.w, shv.w));
            }
            *(float4*)(hs + i * 4) = v;
        }
    }
    const int cg = tid & 31;
    const int rg = tid >> 5;
    float acc[4][4];
    #pragma unroll
    for (int i = 0; i < 4; ++i)
        #pragma unroll
        for (int j = 0; j < 4; ++j) acc[i][j] = 0.f;

    for (int k0 = 0; k0 < DD; k0 += 64) {
        __syncthreads();
        for (int i = tid; i < 64 * DD / 4; i += 256)
            *(float4*)(Ws + i * 4) = *(const float4*)(W + (size_t)k0 * DD + i * 4);
        __syncthreads();
        #pragma unroll 8
        for (int k = 0; k < 64; ++k) {
            float4 wv = *(const float4*)(Ws + k * DD + cg * 4);
            #pragma unroll
            for (int i = 0; i < 4; ++i) {
                float hv = hs[(rg * 4 + i) * DD + k0 + k];
                acc[i][0] = fmaf(hv, wv.x, acc[i][0]);
                acc[i][1] = fmaf(hv, wv.y, acc[i][1]);
                acc[i][2] = fmaf(hv, wv.z, acc[i][2]);
                acc[i][3] = fmaf(hv, wv.w, acc[i][3]);
            }
        }
    }
    float4 bv = *(const float4*)(bias + cg * 4);
    const int cq = cg >> 3;               // chunk index
    const int wo = (cg & 7) * 4;          // within-chunk col
    #pragma unroll
    for (int i = 0; i < 4; ++i) {
        int r = r0 + rg * 4 + i;
        if (r < NSUP) {
            float4 o = make_float4(acc[i][0] + bv.x, acc[i][1] + bv.y,
                                   acc[i][2] + bv.z, acc[i][3] + bv.w);
            size_t co = (size_t)cq * CHSZ + (size_t)r * CW + wo;
            // z (bf16, chunked)
            unsigned int z0 = (unsigned int)f2bf(o.x) | ((unsigned int)f2bf(o.y) << 16);
            unsigned int z1 = (unsigned int)f2bf(o.z) | ((unsigned int)f2bf(o.w) << 16);
            *(uint2*)(zb + co) = make_uint2(z0, z1);
            // y0 = h + z (bf16, chunked)
            float h0 = hs[(rg * 4 + i) * DD + cg * 4 + 0];
            float h1 = hs[(rg * 4 + i) * DD + cg * 4 + 1];
            float h2 = hs[(rg * 4 + i) * DD + cg * 4 + 2];
            float h3 = hs[(rg * 4 + i) * DD + cg * 4 + 3];
            unsigned int p0 = (unsigned int)f2bf(h0 + o.x) | ((unsigned int)f2bf(h1 + o.y) << 16);
            unsigned int p1 = (unsigned int)f2bf(h2 + o.z) | ((unsigned int)f2bf(h3 + o.w) << 16);
            *(uint2*)(y0 + co) = make_uint2(p0, p1);
        }
    }
}

// ---------------- SpMM: chunked operand, quarter-wave per row, blockIdx.y = chunk ----
// FINAL=0: yout[c] = bf16( (A@y)[c]*INV_C + zb[c] )
// FINAL=1: xi5(:, c*CW..) = (A@y)[c]*INV_C   (f32, full layout)
template <int FINAL>
__global__ __launch_bounds__(256) void spmm_c(const unsigned short* __restrict__ yin,
        const int* __restrict__ rp, const int2* __restrict__ epk,
        const unsigned short* __restrict__ zb, float* __restrict__ xi5,
        unsigned short* __restrict__ yout) {
    const int tid = threadIdx.x;
    const int wave = tid >> 6, lane = tid & 63;
    const int q = lane >> 4, ql = lane & 15;
    const int row = blockIdx.x * 16 + wave * 4 + q;
    const int c = blockIdx.y;
    const unsigned short* ybase = yin + (size_t)c * CHSZ;
    const int j0 = rp[row], j1 = rp[row + 1];
    const int co = ql * 2;                // 2 bf16 per lane
    float a0 = 0.f, a1 = 0.f, b0 = 0.f, b1 = 0.f;
    for (int j = j0; j < j1; j += 4) {
        int4 e0 = *(const int4*)(epk + j);
        int4 e1 = *(const int4*)(epk + j + 2);
        unsigned int u0 = *(const unsigned int*)(ybase + (size_t)e0.x * CW + co);
        unsigned int u1 = *(const unsigned int*)(ybase + (size_t)e0.z * CW + co);
        unsigned int u2 = *(const unsigned int*)(ybase + (size_t)e1.x * CW + co);
        unsigned int u3 = *(const unsigned int*)(ybase + (size_t)e1.z * CW + co);
        float w0 = __int_as_float(e0.y), w1 = __int_as_float(e0.w);
        float w2 = __int_as_float(e1.y), w3 = __int_as_float(e1.w);
        a0 = fmaf(w0, bf2f_lo(u0), a0); a1 = fmaf(w0, bf2f_hi(u0), a1);
        b0 = fmaf(w1, bf2f_lo(u1), b0); b1 = fmaf(w1, bf2f_hi(u1), b1);
        a0 = fmaf(w2, bf2f_lo(u2), a0); a1 = fmaf(w2, bf2f_hi(u2), a1);
        b0 = fmaf(w3, bf2f_lo(u3), b0); b1 = fmaf(w3, bf2f_hi(u3), b1);
    }
    float s0 = (a0 + b0) * INV_C, s1 = (a1 + b1) * INV_C;
    if (FINAL) {
        *(float2*)(xi5 + rowoff(row) + c * CW + co) = make_float2(s0, s1);
    } else {
        size_t o = (size_t)c * CHSZ + (size_t)row * CW + co;
        unsigned int zv = *(const unsigned int*)(zb + o);
        s0 += bf2f_lo(zv); s1 += bf2f_hi(zv);
        unsigned int pk = (unsigned int)f2bf(s0) | ((unsigned int)f2bf(s1) << 16);
        *(unsigned int*)(yout + o) = pk;
    }
}

// ---------------- BatchNorm stats (vectorized) ----------------
__global__ __launch_bounds__(256) void bn_stats(const float* __restrict__ xi,
        float* __restrict__ sums) {
    const int cg = threadIdx.x & 31;
    const int rs = threadIdx.x >> 5;
    float4 s = make_float4(0.f, 0.f, 0.f, 0.f);
    float4 qq = make_float4(0.f, 0.f, 0.f, 0.f);
    for (int r = blockIdx.x * 8 + rs; r < NSUP; r += gridDim.x * 8) {
        float4 v = *(const float4*)(xi + rowoff(r) + cg * 4);
        s.x += v.x; s.y += v.y; s.z += v.z; s.w += v.w;
        qq.x = fmaf(v.x, v.x, qq.x); qq.y = fmaf(v.y, v.y, qq.y);
        qq.z = fmaf(v.z, v.z, qq.z); qq.w = fmaf(v.w, v.w, qq.w);
    }
    __shared__ float4 ls[256], lq[256];
    ls[threadIdx.x] = s; lq[threadIdx.x] = qq;
    __syncthreads();
    if (rs == 0) {
        #pragma unroll
        for (int k = 1; k < 8; ++k) {
            float4 ts = ls[k * 32 + cg], tq = lq[k * 32 + cg];
            s.x += ts.x; s.y += ts.y; s.z += ts.z; s.w += ts.w;
            qq.x += tq.x; qq.y += tq.y; qq.z += tq.z; qq.w += tq.w;
        }
        atomicAdd(&sums[cg * 4 + 0], s.x); atomicAdd(&sums[cg * 4 + 1], s.y);
        atomicAdd(&sums[cg * 4 + 2], s.z); atomicAdd(&sums[cg * 4 + 3], s.w);
        atomicAdd(&sums[128 + cg * 4 + 0], qq.x); atomicAdd(&sums[128 + cg * 4 + 1], qq.y);
        atomicAdd(&sums[128 + cg * 4 + 2], qq.z); atomicAdd(&sums[128 + cg * 4 + 3], qq.w);
    }
}

// computes sc/sh, then zeroes stats for the next layer
__global__ void bn_finalize(float* __restrict__ sums, const float* __restrict__ gamma,
        const float* __restrict__ beta, float* __restrict__ sc) {
    int c = threadIdx.x;
    float mean = sums[c] * (1.0f / NSUP);
    float var = sums[128 + c] * (1.0f / NSUP) - mean * mean;
    float scale = gamma[c] / sqrtf(var + BN_EPS_C);
    sc[c] = scale;
    sc[128 + c] = beta[c] - mean * scale;
    __syncthreads();
    sums[c] = 0.f;
    sums[128 + c] = 0.f;
}

// final-layer BN apply (xi5 -> h), h feeds unpool
__global__ __launch_bounds__(256) void bn_apply(const float* __restrict__ xi,
        const float* __restrict__ sc, float* __restrict__ h) {
    int t = blockIdx.x * 256 + threadIdx.x;
    int r = t >> 5, l = t & 31;
    if (r >= NSUP) return;
    float4 v = *(const float4*)(xi + rowoff(r) + l * 4);
    float4 scv = *(const float4*)(sc + l * 4);
    float4 shv = *(const float4*)(sc + 128 + l * 4);
    v.x = lrelu(fmaf(v.x, scv.x, shv.x));
    v.y = lrelu(fmaf(v.y, scv.y, shv.y));
    v.z = lrelu(fmaf(v.z, scv.z, shv.z));
    v.w = lrelu(fmaf(v.w, scv.w, shv.w));
    *(float4*)(h + rowoff(r) + l * 4) = v;
}

// ---------------- unpool ----------------
__global__ __launch_bounds__(256) void unpool(const float* __restrict__ h,
        const int* __restrict__ seg, float* __restrict__ out) {
    int t = blockIdx.x * 256 + threadIdx.x;
    int p = t >> 5, l = t & 31;
    if (p >= NPIX) return;
    int s = seg[p];
    float4 v = *(const float4*)(h + rowoff(s) + l * 4);
    *(float4*)(out + rowoff(p) + l * 4) = v;
}

extern "C" void kernel_launch(void* const* d_in, const int* in_sizes, int n_in,
                              void* d_out, int out_size, void* d_ws, size_t ws_size,
                              hipStream_t stream) {
    const float* x     = (const float*)d_in[0];
    const float* W     = (const float*)d_in[1];
    const float* b     = (const float*)d_in[2];
    const float* gamma = (const float*)d_in[3];
    const float* beta  = (const float*)d_in[4];
    const float* ewt   = (const float*)d_in[5];
    const int*   seg   = (const int*)d_in[6];
    const int*   eidx  = (const int*)d_in[7];
    const int*   esrc  = eidx;
    const int*   edst  = eidx + NE;
    float* out = (float*)d_out;

    // d_out hosts transients (all dead before final unpool):
    //   xi5 f32 25.6MB | zb bf16 12.8MB | ya bf16 12.8MB | yb bf16 12.8MB
    const size_t MAT = (size_t)NSUP * DD;
    float* xi5 = out;
    unsigned short* zb = (unsigned short*)(out + MAT);
    unsigned short* ya = zb + MAT;
    unsigned short* yb = ya + MAT;

    char* ws = (char*)d_ws;
    size_t off = 0;
    auto alloc = [&](size_t bytes) -> void* {
        void* p = ws + off;
        off = (off + bytes + 255) & ~(size_t)255;
        return p;
    };
    float* h       = (float*)alloc(sizeof(float) * MAT);       // 25.6 MB
    int*   rowcnt  = (int*)alloc(sizeof(int) * CNT_CAP);
    int*   rowptr  = (int*)alloc(sizeof(int) * (NSUP + 1));
    int*   rowfill = (int*)alloc(sizeof(int) * NSUP);
    int*   pixcnt  = (int*)alloc(sizeof(int) * CNT_CAP);
    int*   pixptr  = (int*)alloc(sizeof(int) * (NSUP + 1));
    int*   pixfill = (int*)alloc(sizeof(int) * NSUP);
    int*   pixids  = (int*)alloc(sizeof(int) * NPIX);          // 1 MB
    int2*  epk     = (int2*)alloc(sizeof(int2) * NEPAD4);      // 7.6 MB
    float* stats   = (float*)alloc(sizeof(float) * 256);
    float* sc      = (float*)alloc(sizeof(float) * 256);

    hipMemsetAsync(rowcnt, 0, sizeof(int) * CNT_CAP, stream);
    hipMemsetAsync(rowfill, 0, sizeof(int) * NSUP, stream);
    hipMemsetAsync(pixcnt, 0, sizeof(int) * CNT_CAP, stream);
    hipMemsetAsync(pixfill, 0, sizeof(int) * NSUP, stream);
    hipMemsetAsync(epk, 0, sizeof(int2) * NEPAD4, stream);     // pad -> (src 0, w 0.0)
    hipMemsetAsync(stats, 0, sizeof(float) * 256, stream);

    // pixel CSR + pooling
    hist_k<<<(NPIX + 255) / 256, 256, 0, stream>>>(seg, pixcnt, NPIX);
    scan_rowptr<1><<<1, 1024, 0, stream>>>(pixcnt, pixptr);
    pix_scatter<<<(NPIX + 255) / 256, 256, 0, stream>>>(seg, pixptr, pixfill, pixids);
    pool_gather<<<NSUP / 8, 256, 0, stream>>>(x, pixptr, pixids, h);

    // edge CSR by dst, rows padded to multiple of 4, interleaved (src,w)
    hist_k<<<(NE + 255) / 256, 256, 0, stream>>>(edst, rowcnt, NE);
    scan_rowptr<4><<<1, 1024, 0, stream>>>(rowcnt, rowptr);
    edge_scatter<<<(NE + 255) / 256, 256, 0, stream>>>(esrc, edst, ewt, rowptr, rowfill, epk);

    // 5 SFNet layers.  y_t = xi_t + z (bf16, chunked [4][NSUP][32]);
    // xi_{t+1} = A y_t / 2.9.  BN+leaky fused into next GEMM operand load.
    const dim3 sgrid(NSUP / 16, NCH);
    for (int i = 0; i < NL; ++i) {
        if (i == 0)
            gemm_bias<0><<<(NSUP + 31) / 32, 256, 0, stream>>>(h, nullptr,
                    W + (size_t)i * DD * DD, b + i * DD, zb, ya);
        else
            gemm_bias<1><<<(NSUP + 31) / 32, 256, 0, stream>>>(xi5, sc,
                    W + (size_t)i * DD * DD, b + i * DD, zb, ya);

        const unsigned short* ycur = ya;
        unsigned short* ynxt = yb;
        for (int t = 0; t < 4; ++t) {
            spmm_c<0><<<sgrid, 256, 0, stream>>>(ycur, rowptr, epk, zb, nullptr, ynxt);
            const unsigned short* tmp = ycur;
            ycur = ynxt;
            ynxt = (unsigned short*)tmp;
        }
        spmm_c<1><<<sgrid, 256, 0, stream>>>(ycur, rowptr, epk, nullptr, xi5, nullptr);

        bn_stats<<<256, 256, 0, stream>>>(xi5, stats);
        bn_finalize<<<1, 128, 0, stream>>>(stats, gamma + i * DD, beta + i * DD, sc);
    }

    // final layer: BN apply into h (ws), then unpool (overwrites all of d_out)
    bn_apply<<<NSUP * 32 / 256, 256, 0, stream>>>(xi5, sc, h);
    unpool<<<NPIX * 32 / 256, 256, 0, stream>>>(h, seg, out);
}

// Round 6
// 1371.466 us; speedup vs baseline: 1.1849x; 1.1849x over previous
//
#include <hip/hip_runtime.h>

#define NPIX 250000
#define NSUP 50000
#define NE   800000
#define DD   128
#define NL   5

#define BN_EPS_C 1e-5f
#define SLOPE 0.01f
#define INV_C (1.0f / 2.9f)

// feature chunking: 2 chunks x 64 channels -> row-chunk = 128 B = 1 full cache line
#define NCH   2
#define CW    64
#define CHSZ  ((size_t)NSUP * CW)     // elems per chunk (bf16): 6.4 MB

// edge capacity with per-row pad to multiple of 4
#define NEPAD4 (NE + 3 * NSUP)
// scan geometry: 1024 threads x 52 elements, covers 53248 >= NSUP
#define SCAN_PER 52
#define CNT_CAP (1024 * SCAN_PER)

__device__ __forceinline__ size_t rowoff(int r) { return (size_t)r * DD; }

// round-to-nearest-even f32 -> bf16 bits
__device__ __forceinline__ unsigned short f2bf(float f) {
    unsigned int u = __float_as_uint(f);
    unsigned int r = (u + 0x7FFFu + ((u >> 16) & 1u)) >> 16;
    return (unsigned short)r;
}
__device__ __forceinline__ float bf2f_lo(unsigned int v) { return __uint_as_float(v << 16); }
__device__ __forceinline__ float bf2f_hi(unsigned int v) { return __uint_as_float(v & 0xFFFF0000u); }
__device__ __forceinline__ float lrelu(float o) { return o > 0.f ? o : SLOPE * o; }

// ---------------- generic histogram ----------------
__global__ __launch_bounds__(256) void hist_k(const int* __restrict__ ids,
        int* __restrict__ cnt, int n) {
    int e = blockIdx.x * 256 + threadIdx.x;
    if (e >= n) return;
    atomicAdd(cnt + ids[e], 1);
}

// ---------------- single-block scan over padded counters ----------------
template <int PAD>
__global__ __launch_bounds__(1024) void scan_rowptr(const int* __restrict__ cnt,
        int* __restrict__ rp) {
    const int t = threadIdx.x;
    const int lo = t * SCAN_PER;
    int4 c[SCAN_PER / 4];
    int s = 0;
    #pragma unroll
    for (int k = 0; k < SCAN_PER / 4; ++k) {
        int4 v = *(const int4*)(cnt + lo + k * 4);
        if (PAD > 1) {
            v.x = (v.x + PAD - 1) & ~(PAD - 1);
            v.y = (v.y + PAD - 1) & ~(PAD - 1);
            v.z = (v.z + PAD - 1) & ~(PAD - 1);
            v.w = (v.w + PAD - 1) & ~(PAD - 1);
        }
        c[k] = v;
        s += v.x + v.y + v.z + v.w;
    }
    int lane = t & 63, wid = t >> 6;
    int v = s;
    #pragma unroll
    for (int d = 1; d < 64; d <<= 1) {
        int u = __shfl_up(v, d);
        if (lane >= d) v += u;
    }
    __shared__ int wtot[16], woff[16];
    if (lane == 63) wtot[wid] = v;
    __syncthreads();
    if (t == 0) {
        int acc = 0;
        #pragma unroll
        for (int w = 0; w < 16; ++w) { woff[w] = acc; acc += wtot[w]; }
    }
    __syncthreads();
    int base = woff[wid] + v - s;
    #pragma unroll
    for (int k = 0; k < SCAN_PER / 4; ++k) {
        int i = lo + k * 4;
        if (i     <= NSUP) rp[i]     = base;  base += c[k].x;
        if (i + 1 <= NSUP) rp[i + 1] = base;  base += c[k].y;
        if (i + 2 <= NSUP) rp[i + 2] = base;  base += c[k].z;
        if (i + 3 <= NSUP) rp[i + 3] = base;  base += c[k].w;
    }
}

// ---------------- pixel scatter ----------------
__global__ __launch_bounds__(256) void pix_scatter(const int* __restrict__ seg,
        const int* __restrict__ rp, int* __restrict__ fill, int* __restrict__ pix) {
    int p = blockIdx.x * 256 + threadIdx.x;
    if (p >= NPIX) return;
    int s = seg[p];
    int pos = rp[s] + atomicAdd(fill + s, 1);
    pix[pos] = p;
}

// ---------------- edge scatter: interleaved (src, w) pairs ----------------
__global__ __launch_bounds__(256) void edge_scatter(const int* __restrict__ srcv,
        const int* __restrict__ dstv, const float* __restrict__ w,
        const int* __restrict__ rp, int* __restrict__ fill, int2* __restrict__ epk) {
    int e = blockIdx.x * 256 + threadIdx.x;
    if (e >= NE) return;
    int d = dstv[e];
    int pos = rp[d] + atomicAdd(fill + d, 1);
    epk[pos] = make_int2(srcv[e], __float_as_int(w[e]));
}

// ---------------- pooling: half-wave per superpixel, float4 lanes, 4-pixel unroll ----------------
__global__ __launch_bounds__(256) void pool_gather(const float* __restrict__ x,
        const int* __restrict__ pp, const int* __restrict__ pix, float* __restrict__ h) {
    const int tid = threadIdx.x;
    const int wave = tid >> 6, lane = tid & 63;
    const int hf = lane >> 5, hl = lane & 31;
    const int row = blockIdx.x * 8 + wave * 2 + hf;
    const int j0 = pp[row], j1 = pp[row + 1];
    float4 a0 = make_float4(0.f, 0.f, 0.f, 0.f);
    float4 a1 = make_float4(0.f, 0.f, 0.f, 0.f);
    float4 a2 = make_float4(0.f, 0.f, 0.f, 0.f);
    float4 a3 = make_float4(0.f, 0.f, 0.f, 0.f);
    int j = j0;
    for (; j + 3 < j1; j += 4) {
        int p0 = pix[j], p1 = pix[j + 1], p2 = pix[j + 2], p3 = pix[j + 3];
        float4 v0 = *(const float4*)(x + rowoff(p0) + hl * 4);
        float4 v1 = *(const float4*)(x + rowoff(p1) + hl * 4);
        float4 v2 = *(const float4*)(x + rowoff(p2) + hl * 4);
        float4 v3 = *(const float4*)(x + rowoff(p3) + hl * 4);
        a0.x += v0.x; a0.y += v0.y; a0.z += v0.z; a0.w += v0.w;
        a1.x += v1.x; a1.y += v1.y; a1.z += v1.z; a1.w += v1.w;
        a2.x += v2.x; a2.y += v2.y; a2.z += v2.z; a2.w += v2.w;
        a3.x += v3.x; a3.y += v3.y; a3.z += v3.z; a3.w += v3.w;
    }
    for (; j < j1; ++j) {
        int p0 = pix[j];
        float4 v0 = *(const float4*)(x + rowoff(p0) + hl * 4);
        a0.x += v0.x; a0.y += v0.y; a0.z += v0.z; a0.w += v0.w;
    }
    float inv = 1.0f / fmaxf((float)(j1 - j0), 1.0f);
    float4 o = make_float4((a0.x + a1.x + a2.x + a3.x) * inv,
                           (a0.y + a1.y + a2.y + a3.y) * inv,
                           (a0.z + a1.z + a2.z + a3.z) * inv,
                           (a0.w + a1.w + a2.w + a3.w) * inv);
    *(float4*)(h + rowoff(row) + hl * 4) = o;
}

// ---------------- GEMM: z = act(hin) @ W + b ; y0 = bf16(act(hin) + z) ----------------
// z, y0 written in CHUNKED layout [NCH][NSUP][CW].
// FUSE=1: act(v) = leaky(v*sc + sh)  (BN of previous layer applied on load)
template <int FUSE>
__global__ __launch_bounds__(256) void gemm_bias(const float* __restrict__ hin,
        const float* __restrict__ scsh, const float* __restrict__ W,
        const float* __restrict__ bias,
        unsigned short* __restrict__ zb, unsigned short* __restrict__ y0) {
    __shared__ float hs[32 * DD];   // 16 KB
    __shared__ float Ws[64 * DD];   // 32 KB
    const int tid = threadIdx.x;
    const int r0 = blockIdx.x * 32;
    {
        for (int i = tid; i < 32 * DD / 4; i += 256) {
            int row = i >> 5;
            float4 v = make_float4(0.f, 0.f, 0.f, 0.f);
            if (r0 + row < NSUP) v = *(const float4*)(hin + rowoff(r0 + row) + (i & 31) * 4);
            if (FUSE) {
                float4 scv = *(const float4*)(scsh + (i & 31) * 4);
                float4 shv = *(const float4*)(scsh + 128 + (i & 31) * 4);
                v.x = lrelu(fmaf(v.x, scv.x, shv.x));
                v.y = lrelu(fmaf(v.y, scv.y, shv.y));
                v.z = lrelu(fmaf(v.z, scv.z, shv.z));
                v.w = lrelu(fmaf(v.w, scv.w, shv.w));
            }
            *(float4*)(hs + i * 4) = v;
        }
    }
    const int cg = tid & 31;
    const int rg = tid >> 5;
    float acc[4][4];
    #pragma unroll
    for (int i = 0; i < 4; ++i)
        #pragma unroll
        for (int j = 0; j < 4; ++j) acc[i][j] = 0.f;

    for (int k0 = 0; k0 < DD; k0 += 64) {
        __syncthreads();
        for (int i = tid; i < 64 * DD / 4; i += 256)
            *(float4*)(Ws + i * 4) = *(const float4*)(W + (size_t)k0 * DD + i * 4);
        __syncthreads();
        #pragma unroll 8
        for (int k = 0; k < 64; ++k) {
            float4 wv = *(const float4*)(Ws + k * DD + cg * 4);
            #pragma unroll
            for (int i = 0; i < 4; ++i) {
                float hv = hs[(rg * 4 + i) * DD + k0 + k];
                acc[i][0] = fmaf(hv, wv.x, acc[i][0]);
                acc[i][1] = fmaf(hv, wv.y, acc[i][1]);
                acc[i][2] = fmaf(hv, wv.z, acc[i][2]);
                acc[i][3] = fmaf(hv, wv.w, acc[i][3]);
            }
        }
    }
    float4 bv = *(const float4*)(bias + cg * 4);
    const int cq = cg >> 4;               // chunk index (0/1)
    const int wo = (cg & 15) * 4;         // within-chunk col
    #pragma unroll
    for (int i = 0; i < 4; ++i) {
        int r = r0 + rg * 4 + i;
        if (r < NSUP) {
            float4 o = make_float4(acc[i][0] + bv.x, acc[i][1] + bv.y,
                                   acc[i][2] + bv.z, acc[i][3] + bv.w);
            size_t co = (size_t)cq * CHSZ + (size_t)r * CW + wo;
            // z (bf16, chunked)
            unsigned int z0 = (unsigned int)f2bf(o.x) | ((unsigned int)f2bf(o.y) << 16);
            unsigned int z1 = (unsigned int)f2bf(o.z) | ((unsigned int)f2bf(o.w) << 16);
            *(uint2*)(zb + co) = make_uint2(z0, z1);
            // y0 = h + z (bf16, chunked)
            float h0 = hs[(rg * 4 + i) * DD + cg * 4 + 0];
            float h1 = hs[(rg * 4 + i) * DD + cg * 4 + 1];
            float h2 = hs[(rg * 4 + i) * DD + cg * 4 + 2];
            float h3 = hs[(rg * 4 + i) * DD + cg * 4 + 3];
            unsigned int p0 = (unsigned int)f2bf(h0 + o.x) | ((unsigned int)f2bf(h1 + o.y) << 16);
            unsigned int p1 = (unsigned int)f2bf(h2 + o.z) | ((unsigned int)f2bf(h3 + o.w) << 16);
            *(uint2*)(y0 + co) = make_uint2(p0, p1);
        }
    }
}

// ---------------- SpMM: chunked operand (full 128B line/row-chunk), quarter-wave per row ----
// FINAL=0: yout[c] = bf16( (A@y)[c]*INV_C + zb[c] )
// FINAL=1: xi5(:, c*CW..) = (A@y)[c]*INV_C   (f32, full layout)
template <int FINAL>
__global__ __launch_bounds__(256) void spmm_c(const unsigned short* __restrict__ yin,
        const int* __restrict__ rp, const int2* __restrict__ epk,
        const unsigned short* __restrict__ zb, float* __restrict__ xi5,
        unsigned short* __restrict__ yout) {
    const int tid = threadIdx.x;
    const int wave = tid >> 6, lane = tid & 63;
    const int q = lane >> 4, ql = lane & 15;
    const int row = blockIdx.x * 16 + wave * 4 + q;
    const int c = blockIdx.y;
    const unsigned short* ybase = yin + (size_t)c * CHSZ;
    const int j0 = rp[row], j1 = rp[row + 1];
    const int co = ql * 4;                // 4 bf16 per lane (8B)
    float a0 = 0.f, a1 = 0.f, a2 = 0.f, a3 = 0.f;
    float b0 = 0.f, b1 = 0.f, b2 = 0.f, b3 = 0.f;
    for (int j = j0; j < j1; j += 4) {
        int4 e0 = *(const int4*)(epk + j);
        int4 e1 = *(const int4*)(epk + j + 2);
        uint2 u0 = *(const uint2*)(ybase + (size_t)e0.x * CW + co);
        uint2 u1 = *(const uint2*)(ybase + (size_t)e0.z * CW + co);
        uint2 u2 = *(const uint2*)(ybase + (size_t)e1.x * CW + co);
        uint2 u3 = *(const uint2*)(ybase + (size_t)e1.z * CW + co);
        float w0 = __int_as_float(e0.y), w1 = __int_as_float(e0.w);
        float w2 = __int_as_float(e1.y), w3 = __int_as_float(e1.w);
        a0 = fmaf(w0, bf2f_lo(u0.x), a0); a1 = fmaf(w0, bf2f_hi(u0.x), a1);
        a2 = fmaf(w0, bf2f_lo(u0.y), a2); a3 = fmaf(w0, bf2f_hi(u0.y), a3);
        b0 = fmaf(w1, bf2f_lo(u1.x), b0); b1 = fmaf(w1, bf2f_hi(u1.x), b1);
        b2 = fmaf(w1, bf2f_lo(u1.y), b2); b3 = fmaf(w1, bf2f_hi(u1.y), b3);
        a0 = fmaf(w2, bf2f_lo(u2.x), a0); a1 = fmaf(w2, bf2f_hi(u2.x), a1);
        a2 = fmaf(w2, bf2f_lo(u2.y), a2); a3 = fmaf(w2, bf2f_hi(u2.y), a3);
        b0 = fmaf(w3, bf2f_lo(u3.x), b0); b1 = fmaf(w3, bf2f_hi(u3.x), b1);
        b2 = fmaf(w3, bf2f_lo(u3.y), b2); b3 = fmaf(w3, bf2f_hi(u3.y), b3);
    }
    float s0 = (a0 + b0) * INV_C, s1 = (a1 + b1) * INV_C;
    float s2 = (a2 + b2) * INV_C, s3 = (a3 + b3) * INV_C;
    if (FINAL) {
        *(float4*)(xi5 + rowoff(row) + c * CW + co) = make_float4(s0, s1, s2, s3);
    } else {
        size_t o = (size_t)c * CHSZ + (size_t)row * CW + co;
        uint2 zv = *(const uint2*)(zb + o);
        s0 += bf2f_lo(zv.x); s1 += bf2f_hi(zv.x);
        s2 += bf2f_lo(zv.y); s3 += bf2f_hi(zv.y);
        uint2 pk;
        pk.x = (unsigned int)f2bf(s0) | ((unsigned int)f2bf(s1) << 16);
        pk.y = (unsigned int)f2bf(s2) | ((unsigned int)f2bf(s3) << 16);
        *(uint2*)(yout + o) = pk;
    }
}

// ---------------- BatchNorm stats (vectorized) ----------------
__global__ __launch_bounds__(256) void bn_stats(const float* __restrict__ xi,
        float* __restrict__ sums) {
    const int cg = threadIdx.x & 31;
    const int rs = threadIdx.x >> 5;
    float4 s = make_float4(0.f, 0.f, 0.f, 0.f);
    float4 qq = make_float4(0.f, 0.f, 0.f, 0.f);
    for (int r = blockIdx.x * 8 + rs; r < NSUP; r += gridDim.x * 8) {
        float4 v = *(const float4*)(xi + rowoff(r) + cg * 4);
        s.x += v.x; s.y += v.y; s.z += v.z; s.w += v.w;
        qq.x = fmaf(v.x, v.x, qq.x); qq.y = fmaf(v.y, v.y, qq.y);
        qq.z = fmaf(v.z, v.z, qq.z); qq.w = fmaf(v.w, v.w, qq.w);
    }
    __shared__ float4 ls[256], lq[256];
    ls[threadIdx.x] = s; lq[threadIdx.x] = qq;
    __syncthreads();
    if (rs == 0) {
        #pragma unroll
        for (int k = 1; k < 8; ++k) {
            float4 ts = ls[k * 32 + cg], tq = lq[k * 32 + cg];
            s.x += ts.x; s.y += ts.y; s.z += ts.z; s.w += ts.w;
            qq.x += tq.x; qq.y += tq.y; qq.z += tq.z; qq.w += tq.w;
        }
        atomicAdd(&sums[cg * 4 + 0], s.x); atomicAdd(&sums[cg * 4 + 1], s.y);
        atomicAdd(&sums[cg * 4 + 2], s.z); atomicAdd(&sums[cg * 4 + 3], s.w);
        atomicAdd(&sums[128 + cg * 4 + 0], qq.x); atomicAdd(&sums[128 + cg * 4 + 1], qq.y);
        atomicAdd(&sums[128 + cg * 4 + 2], qq.z); atomicAdd(&sums[128 + cg * 4 + 3], qq.w);
    }
}

// computes sc/sh, then zeroes stats for the next layer
__global__ void bn_finalize(float* __restrict__ sums, const float* __restrict__ gamma,
        const float* __restrict__ beta, float* __restrict__ sc) {
    int c = threadIdx.x;
    float mean = sums[c] * (1.0f / NSUP);
    float var = sums[128 + c] * (1.0f / NSUP) - mean * mean;
    float scale = gamma[c] / sqrtf(var + BN_EPS_C);
    sc[c] = scale;
    sc[128 + c] = beta[c] - mean * scale;
    __syncthreads();
    sums[c] = 0.f;
    sums[128 + c] = 0.f;
}

// final-layer BN apply (xi5 -> h), h feeds unpool
__global__ __launch_bounds__(256) void bn_apply(const float* __restrict__ xi,
        const float* __restrict__ sc, float* __restrict__ h) {
    int t = blockIdx.x * 256 + threadIdx.x;
    int r = t >> 5, l = t & 31;
    if (r >= NSUP) return;
    float4 v = *(const float4*)(xi + rowoff(r) + l * 4);
    float4 scv = *(const float4*)(sc + l * 4);
    float4 shv = *(const float4*)(sc + 128 + l * 4);
    v.x = lrelu(fmaf(v.x, scv.x, shv.x));
    v.y = lrelu(fmaf(v.y, scv.y, shv.y));
    v.z = lrelu(fmaf(v.z, scv.z, shv.z));
    v.w = lrelu(fmaf(v.w, scv.w, shv.w));
    *(float4*)(h + rowoff(r) + l * 4) = v;
}

// ---------------- unpool ----------------
__global__ __launch_bounds__(256) void unpool(const float* __restrict__ h,
        const int* __restrict__ seg, float* __restrict__ out) {
    int t = blockIdx.x * 256 + threadIdx.x;
    int p = t >> 5, l = t & 31;
    if (p >= NPIX) return;
    int s = seg[p];
    float4 v = *(const float4*)(h + rowoff(s) + l * 4);
    *(float4*)(out + rowoff(p) + l * 4) = v;
}

extern "C" void kernel_launch(void* const* d_in, const int* in_sizes, int n_in,
                              void* d_out, int out_size, void* d_ws, size_t ws_size,
                              hipStream_t stream) {
    const float* x     = (const float*)d_in[0];
    const float* W     = (const float*)d_in[1];
    const float* b     = (const float*)d_in[2];
    const float* gamma = (const float*)d_in[3];
    const float* beta  = (const float*)d_in[4];
    const float* ewt   = (const float*)d_in[5];
    const int*   seg   = (const int*)d_in[6];
    const int*   eidx  = (const int*)d_in[7];
    const int*   esrc  = eidx;
    const int*   edst  = eidx + NE;
    float* out = (float*)d_out;

    // d_out hosts transients (all dead before final unpool):
    //   xi5 f32 25.6MB | zb bf16 12.8MB | ya bf16 12.8MB | yb bf16 12.8MB
    const size_t MAT = (size_t)NSUP * DD;
    float* xi5 = out;
    unsigned short* zb = (unsigned short*)(out + MAT);
    unsigned short* ya = zb + MAT;
    unsigned short* yb = ya + MAT;

    char* ws = (char*)d_ws;
    size_t off = 0;
    auto alloc = [&](size_t bytes) -> void* {
        void* p = ws + off;
        off = (off + bytes + 255) & ~(size_t)255;
        return p;
    };
    float* h       = (float*)alloc(sizeof(float) * MAT);       // 25.6 MB
    int*   rowcnt  = (int*)alloc(sizeof(int) * CNT_CAP);
    int*   rowptr  = (int*)alloc(sizeof(int) * (NSUP + 1));
    int*   rowfill = (int*)alloc(sizeof(int) * NSUP);
    int*   pixcnt  = (int*)alloc(sizeof(int) * CNT_CAP);
    int*   pixptr  = (int*)alloc(sizeof(int) * (NSUP + 1));
    int*   pixfill = (int*)alloc(sizeof(int) * NSUP);
    int*   pixids  = (int*)alloc(sizeof(int) * NPIX);          // 1 MB
    int2*  epk     = (int2*)alloc(sizeof(int2) * NEPAD4);      // 7.6 MB
    float* stats   = (float*)alloc(sizeof(float) * 256);
    float* sc      = (float*)alloc(sizeof(float) * 256);

    hipMemsetAsync(rowcnt, 0, sizeof(int) * CNT_CAP, stream);
    hipMemsetAsync(rowfill, 0, sizeof(int) * NSUP, stream);
    hipMemsetAsync(pixcnt, 0, sizeof(int) * CNT_CAP, stream);
    hipMemsetAsync(pixfill, 0, sizeof(int) * NSUP, stream);
    hipMemsetAsync(epk, 0, sizeof(int2) * NEPAD4, stream);     // pad -> (src 0, w 0.0)
    hipMemsetAsync(stats, 0, sizeof(float) * 256, stream);

    // pixel CSR + pooling
    hist_k<<<(NPIX + 255) / 256, 256, 0, stream>>>(seg, pixcnt, NPIX);
    scan_rowptr<1><<<1, 1024, 0, stream>>>(pixcnt, pixptr);
    pix_scatter<<<(NPIX + 255) / 256, 256, 0, stream>>>(seg, pixptr, pixfill, pixids);
    pool_gather<<<NSUP / 8, 256, 0, stream>>>(x, pixptr, pixids, h);

    // edge CSR by dst, rows padded to multiple of 4, interleaved (src,w)
    hist_k<<<(NE + 255) / 256, 256, 0, stream>>>(edst, rowcnt, NE);
    scan_rowptr<4><<<1, 1024, 0, stream>>>(rowcnt, rowptr);
    edge_scatter<<<(NE + 255) / 256, 256, 0, stream>>>(esrc, edst, ewt, rowptr, rowfill, epk);

    // 5 SFNet layers.  y_t = xi_t + z (bf16, chunked [2][NSUP][64]);
    // xi_{t+1} = A y_t / 2.9.  BN+leaky fused into next GEMM operand load.
    const dim3 sgrid(NSUP / 16, NCH);
    for (int i = 0; i < NL; ++i) {
        if (i == 0)
            gemm_bias<0><<<(NSUP + 31) / 32, 256, 0, stream>>>(h, nullptr,
                    W + (size_t)i * DD * DD, b + i * DD, zb, ya);
        else
            gemm_bias<1><<<(NSUP + 31) / 32, 256, 0, stream>>>(xi5, sc,
                    W + (size_t)i * DD * DD, b + i * DD, zb, ya);

        const unsigned short* ycur = ya;
        unsigned short* ynxt = yb;
        for (int t = 0; t < 4; ++t) {
            spmm_c<0><<<sgrid, 256, 0, stream>>>(ycur, rowptr, epk, zb, nullptr, ynxt);
            const unsigned short* tmp = ycur;
            ycur = ynxt;
            ynxt = (unsigned short*)tmp;
        }
        spmm_c<1><<<sgrid, 256, 0, stream>>>(ycur, rowptr, epk, nullptr, xi5, nullptr);

        bn_stats<<<256, 256, 0, stream>>>(xi5, stats);
        bn_finalize<<<1, 128, 0, stream>>>(stats, gamma + i * DD, beta + i * DD, sc);
    }

    // final layer: BN apply into h (ws), then unpool (overwrites all of d_out)
    bn_apply<<<NSUP * 32 / 256, 256, 0, stream>>>(xi5, sc, h);
    unpool<<<NPIX * 32 / 256, 256, 0, stream>>>(h, seg, out);
}

// Round 7
// 1318.598 us; speedup vs baseline: 1.2324x; 1.0401x over previous
//
#include <hip/hip_runtime.h>

#define NPIX 250000
#define NSUP 50000
#define NE   800000
#define DD   128
#define NL   5

#define BN_EPS_C 1e-5f
#define SLOPE 0.01f
#define INV_C (1.0f / 2.9f)

// feature chunking kept from r6 for z/y buffers: [2][NSUP][64] bf16
#define NCH   2
#define CW    64
#define CHSZ  ((size_t)NSUP * CW)

// edge capacity with per-row pad to multiple of 4
#define NEPAD4 (NE + 3 * NSUP)
#define SCAN_PER 52
#define CNT_CAP (1024 * SCAN_PER)

typedef __attribute__((ext_vector_type(8))) short short8v;   // 8 bf16 (4 VGPR)
typedef __attribute__((ext_vector_type(4))) float f32x4;     // MFMA acc

__device__ __forceinline__ size_t rowoff(int r) { return (size_t)r * DD; }

__device__ __forceinline__ unsigned short f2bf(float f) {
    unsigned int u = __float_as_uint(f);
    unsigned int r = (u + 0x7FFFu + ((u >> 16) & 1u)) >> 16;
    return (unsigned short)r;
}
__device__ __forceinline__ float bf2f_lo(unsigned int v) { return __uint_as_float(v << 16); }
__device__ __forceinline__ float bf2f_hi(unsigned int v) { return __uint_as_float(v & 0xFFFF0000u); }
__device__ __forceinline__ float lrelu(float o) { return o > 0.f ? o : SLOPE * o; }

// ---------------- generic histogram ----------------
__global__ __launch_bounds__(256) void hist_k(const int* __restrict__ ids,
        int* __restrict__ cnt, int n) {
    int e = blockIdx.x * 256 + threadIdx.x;
    if (e >= n) return;
    atomicAdd(cnt + ids[e], 1);
}

// ---------------- single-block scan over padded counters ----------------
template <int PAD>
__global__ __launch_bounds__(1024) void scan_rowptr(const int* __restrict__ cnt,
        int* __restrict__ rp) {
    const int t = threadIdx.x;
    const int lo = t * SCAN_PER;
    int4 c[SCAN_PER / 4];
    int s = 0;
    #pragma unroll
    for (int k = 0; k < SCAN_PER / 4; ++k) {
        int4 v = *(const int4*)(cnt + lo + k * 4);
        if (PAD > 1) {
            v.x = (v.x + PAD - 1) & ~(PAD - 1);
            v.y = (v.y + PAD - 1) & ~(PAD - 1);
            v.z = (v.z + PAD - 1) & ~(PAD - 1);
            v.w = (v.w + PAD - 1) & ~(PAD - 1);
        }
        c[k] = v;
        s += v.x + v.y + v.z + v.w;
    }
    int lane = t & 63, wid = t >> 6;
    int v = s;
    #pragma unroll
    for (int d = 1; d < 64; d <<= 1) {
        int u = __shfl_up(v, d);
        if (lane >= d) v += u;
    }
    __shared__ int wtot[16], woff[16];
    if (lane == 63) wtot[wid] = v;
    __syncthreads();
    if (t == 0) {
        int acc = 0;
        #pragma unroll
        for (int w = 0; w < 16; ++w) { woff[w] = acc; acc += wtot[w]; }
    }
    __syncthreads();
    int base = woff[wid] + v - s;
    #pragma unroll
    for (int k = 0; k < SCAN_PER / 4; ++k) {
        int i = lo + k * 4;
        if (i     <= NSUP) rp[i]     = base;  base += c[k].x;
        if (i + 1 <= NSUP) rp[i + 1] = base;  base += c[k].y;
        if (i + 2 <= NSUP) rp[i + 2] = base;  base += c[k].z;
        if (i + 3 <= NSUP) rp[i + 3] = base;  base += c[k].w;
    }
}

// ---------------- pixel scatter ----------------
__global__ __launch_bounds__(256) void pix_scatter(const int* __restrict__ seg,
        const int* __restrict__ rp, int* __restrict__ fill, int* __restrict__ pix) {
    int p = blockIdx.x * 256 + threadIdx.x;
    if (p >= NPIX) return;
    int s = seg[p];
    int pos = rp[s] + atomicAdd(fill + s, 1);
    pix[pos] = p;
}

// ---------------- edge scatter: interleaved (src, w) pairs ----------------
__global__ __launch_bounds__(256) void edge_scatter(const int* __restrict__ srcv,
        const int* __restrict__ dstv, const float* __restrict__ w,
        const int* __restrict__ rp, int* __restrict__ fill, int2* __restrict__ epk) {
    int e = blockIdx.x * 256 + threadIdx.x;
    if (e >= NE) return;
    int d = dstv[e];
    int pos = rp[d] + atomicAdd(fill + d, 1);
    epk[pos] = make_int2(srcv[e], __float_as_int(w[e]));
}

// ---------------- W transpose + bf16 convert: Wtb[l][n][k] = bf16(W[l][k][n]) ----------------
__global__ __launch_bounds__(256) void wconv(const float* __restrict__ W,
        unsigned short* __restrict__ Wtb) {
    int t = blockIdx.x * 256 + threadIdx.x;
    if (t >= NL * DD * DD) return;
    int l = t / (DD * DD);
    int rem = t - l * (DD * DD);
    int n = rem >> 7, k = rem & 127;
    Wtb[t] = f2bf(W[(size_t)l * DD * DD + (size_t)k * DD + n]);
}

// ---------------- pooling: half-wave per superpixel, 4-pixel unroll, bf16 out ----------------
__global__ __launch_bounds__(256) void pool_gather(const float* __restrict__ x,
        const int* __restrict__ pp, const int* __restrict__ pix, unsigned short* __restrict__ hb) {
    const int tid = threadIdx.x;
    const int wave = tid >> 6, lane = tid & 63;
    const int hf = lane >> 5, hl = lane & 31;
    const int row = blockIdx.x * 8 + wave * 2 + hf;
    const int j0 = pp[row], j1 = pp[row + 1];
    float4 a0 = make_float4(0.f, 0.f, 0.f, 0.f);
    float4 a1 = make_float4(0.f, 0.f, 0.f, 0.f);
    float4 a2 = make_float4(0.f, 0.f, 0.f, 0.f);
    float4 a3 = make_float4(0.f, 0.f, 0.f, 0.f);
    int j = j0;
    for (; j + 3 < j1; j += 4) {
        int p0 = pix[j], p1 = pix[j + 1], p2 = pix[j + 2], p3 = pix[j + 3];
        float4 v0 = *(const float4*)(x + rowoff(p0) + hl * 4);
        float4 v1 = *(const float4*)(x + rowoff(p1) + hl * 4);
        float4 v2 = *(const float4*)(x + rowoff(p2) + hl * 4);
        float4 v3 = *(const float4*)(x + rowoff(p3) + hl * 4);
        a0.x += v0.x; a0.y += v0.y; a0.z += v0.z; a0.w += v0.w;
        a1.x += v1.x; a1.y += v1.y; a1.z += v1.z; a1.w += v1.w;
        a2.x += v2.x; a2.y += v2.y; a2.z += v2.z; a2.w += v2.w;
        a3.x += v3.x; a3.y += v3.y; a3.z += v3.z; a3.w += v3.w;
    }
    for (; j < j1; ++j) {
        int p0 = pix[j];
        float4 v0 = *(const float4*)(x + rowoff(p0) + hl * 4);
        a0.x += v0.x; a0.y += v0.y; a0.z += v0.z; a0.w += v0.w;
    }
    float inv = 1.0f / fmaxf((float)(j1 - j0), 1.0f);
    float o0 = (a0.x + a1.x + a2.x + a3.x) * inv;
    float o1 = (a0.y + a1.y + a2.y + a3.y) * inv;
    float o2 = (a0.z + a1.z + a2.z + a3.z) * inv;
    float o3 = (a0.w + a1.w + a2.w + a3.w) * inv;
    uint2 pk;
    pk.x = (unsigned int)f2bf(o0) | ((unsigned int)f2bf(o1) << 16);
    pk.y = (unsigned int)f2bf(o2) | ((unsigned int)f2bf(o3) << 16);
    *(uint2*)(hb + rowoff(row) + hl * 4) = pk;
}

// ---------------- MFMA GEMM: z = act(xib) @ W + b -> zb (chunked bf16) ----------------
// A operand: xib [NSUP][128] bf16 (FUSE=1: apply BN scale/shift + leaky on load).
// B operand: Wtb layer slice [n][k] bf16 (transposed W).
// Wave: 32 rows x 128 cols; block 128 threads = 2 waves = 64 rows.
template <int FUSE>
__global__ __launch_bounds__(128) void gemm_mfma(const unsigned short* __restrict__ xib,
        const float* __restrict__ scsh, const unsigned short* __restrict__ Wtb,
        const float* __restrict__ bias, unsigned short* __restrict__ zb) {
    const int wv = threadIdx.x >> 6;
    const int l  = threadIdx.x & 63;
    const int lr = l & 15;
    const int lk = (l >> 4) * 8;
    const int rbase = blockIdx.x * 64 + wv * 32;

    f32x4 acc[2][8];
    #pragma unroll
    for (int rt = 0; rt < 2; ++rt)
        #pragma unroll
        for (int nt = 0; nt < 8; ++nt)
            acc[rt][nt] = (f32x4){0.f, 0.f, 0.f, 0.f};

    #pragma unroll
    for (int kt = 0; kt < 4; ++kt) {
        const int kk = kt * 32 + lk;
        short8v bfr[8];
        #pragma unroll
        for (int nt = 0; nt < 8; ++nt)
            bfr[nt] = *(const short8v*)(Wtb + (size_t)(nt * 16 + lr) * DD + kk);
        float4 scv0, scv1, shv0, shv1;
        if (FUSE) {
            scv0 = *(const float4*)(scsh + kk);
            scv1 = *(const float4*)(scsh + kk + 4);
            shv0 = *(const float4*)(scsh + 128 + kk);
            shv1 = *(const float4*)(scsh + 128 + kk + 4);
        }
        #pragma unroll
        for (int rt = 0; rt < 2; ++rt) {
            int r = rbase + rt * 16 + lr;
            if (r >= NSUP) r = NSUP - 1;
            short8v a;
            if (FUSE) {
                uint4 av = *(const uint4*)(xib + (size_t)r * DD + kk);
                float f0 = lrelu(fmaf(bf2f_lo(av.x), scv0.x, shv0.x));
                float f1 = lrelu(fmaf(bf2f_hi(av.x), scv0.y, shv0.y));
                float f2 = lrelu(fmaf(bf2f_lo(av.y), scv0.z, shv0.z));
                float f3 = lrelu(fmaf(bf2f_hi(av.y), scv0.w, shv0.w));
                float f4 = lrelu(fmaf(bf2f_lo(av.z), scv1.x, shv1.x));
                float f5 = lrelu(fmaf(bf2f_hi(av.z), scv1.y, shv1.y));
                float f6 = lrelu(fmaf(bf2f_lo(av.w), scv1.z, shv1.z));
                float f7 = lrelu(fmaf(bf2f_hi(av.w), scv1.w, shv1.w));
                a[0] = (short)f2bf(f0); a[1] = (short)f2bf(f1);
                a[2] = (short)f2bf(f2); a[3] = (short)f2bf(f3);
                a[4] = (short)f2bf(f4); a[5] = (short)f2bf(f5);
                a[6] = (short)f2bf(f6); a[7] = (short)f2bf(f7);
            } else {
                a = *(const short8v*)(xib + (size_t)r * DD + kk);
            }
            #pragma unroll
            for (int nt = 0; nt < 8; ++nt)
                acc[rt][nt] = __builtin_amdgcn_mfma_f32_16x16x32_bf16(a, bfr[nt], acc[rt][nt], 0, 0, 0);
        }
    }
    // epilogue: D layout col = l&15, row = (l>>4)*4 + j  [m89-verified]
    #pragma unroll
    for (int rt = 0; rt < 2; ++rt) {
        const int orow = rbase + rt * 16 + (l >> 4) * 4;
        #pragma unroll
        for (int nt = 0; nt < 8; ++nt) {
            const int col = nt * 16 + lr;
            const float bs = bias[col];
            const int ch = col >> 6;
            const int cc = col & 63;
            #pragma unroll
            for (int j = 0; j < 4; ++j) {
                int r = orow + j;
                if (r < NSUP)
                    zb[(size_t)ch * CHSZ + (size_t)r * CW + cc] = f2bf(acc[rt][nt][j] + bs);
            }
        }
    }
}

// ---------------- y0 = bf16( act(xib) + z )  (elementwise; chunked output) ----------------
template <int FUSE>
__global__ __launch_bounds__(256) void make_y0(const unsigned short* __restrict__ xib,
        const float* __restrict__ scsh, const unsigned short* __restrict__ zbc,
        unsigned short* __restrict__ ya) {
    int t = blockIdx.x * 256 + threadIdx.x;     // NSUP*16
    int r = t >> 4, g = t & 15;
    int col = g * 8;
    uint4 xv = *(const uint4*)(xib + (size_t)r * DD + col);
    float f0 = bf2f_lo(xv.x), f1 = bf2f_hi(xv.x), f2 = bf2f_lo(xv.y), f3 = bf2f_hi(xv.y);
    float f4 = bf2f_lo(xv.z), f5 = bf2f_hi(xv.z), f6 = bf2f_lo(xv.w), f7 = bf2f_hi(xv.w);
    if (FUSE) {
        float4 sc0 = *(const float4*)(scsh + col), sc1 = *(const float4*)(scsh + col + 4);
        float4 sh0 = *(const float4*)(scsh + 128 + col), sh1 = *(const float4*)(scsh + 128 + col + 4);
        f0 = lrelu(fmaf(f0, sc0.x, sh0.x)); f1 = lrelu(fmaf(f1, sc0.y, sh0.y));
        f2 = lrelu(fmaf(f2, sc0.z, sh0.z)); f3 = lrelu(fmaf(f3, sc0.w, sh0.w));
        f4 = lrelu(fmaf(f4, sc1.x, sh1.x)); f5 = lrelu(fmaf(f5, sc1.y, sh1.y));
        f6 = lrelu(fmaf(f6, sc1.z, sh1.z)); f7 = lrelu(fmaf(f7, sc1.w, sh1.w));
    }
    int ch = col >> 6, cc = col & 63;
    size_t zo = (size_t)ch * CHSZ + (size_t)r * CW + cc;
    uint4 zv = *(const uint4*)(zbc + zo);
    f0 += bf2f_lo(zv.x); f1 += bf2f_hi(zv.x);
    f2 += bf2f_lo(zv.y); f3 += bf2f_hi(zv.y);
    f4 += bf2f_lo(zv.z); f5 += bf2f_hi(zv.z);
    f6 += bf2f_lo(zv.w); f7 += bf2f_hi(zv.w);
    uint4 o;
    o.x = (unsigned int)f2bf(f0) | ((unsigned int)f2bf(f1) << 16);
    o.y = (unsigned int)f2bf(f2) | ((unsigned int)f2bf(f3) << 16);
    o.z = (unsigned int)f2bf(f4) | ((unsigned int)f2bf(f5) << 16);
    o.w = (unsigned int)f2bf(f6) | ((unsigned int)f2bf(f7) << 16);
    *(uint4*)(ya + zo) = o;
}

// ---------------- SpMM: chunked operand, quarter-wave per row, 8-deep gather ILP ----------
// FINAL=0: yout[c] = bf16( (A@y)[c]*INV_C + zb[c] )   (chunked)
// FINAL=1: xibout(:, c*64..) = bf16( (A@y)[c]*INV_C ) (row-major [NSUP][128])
template <int FINAL>
__global__ __launch_bounds__(256) void spmm_c(const unsigned short* __restrict__ yin,
        const int* __restrict__ rp, const int2* __restrict__ epk,
        const unsigned short* __restrict__ zb, unsigned short* __restrict__ xibout,
        unsigned short* __restrict__ yout) {
    const int tid = threadIdx.x;
    const int wave = tid >> 6, lane = tid & 63;
    const int q = lane >> 4, ql = lane & 15;
    const int row = blockIdx.x * 16 + wave * 4 + q;
    const int c = blockIdx.y;
    const unsigned short* ybase = yin + (size_t)c * CHSZ;
    const int j0 = rp[row], j1 = rp[row + 1];
    const int co = ql * 4;
    float a0 = 0.f, a1 = 0.f, a2 = 0.f, a3 = 0.f;
    float b0 = 0.f, b1 = 0.f, b2 = 0.f, b3 = 0.f;
    int j = j0;
    for (; j + 8 <= j1; j += 8) {
        int4 e0 = *(const int4*)(epk + j);
        int4 e1 = *(const int4*)(epk + j + 2);
        int4 e2 = *(const int4*)(epk + j + 4);
        int4 e3 = *(const int4*)(epk + j + 6);
        uint2 u0 = *(const uint2*)(ybase + (size_t)e0.x * CW + co);
        uint2 u1 = *(const uint2*)(ybase + (size_t)e0.z * CW + co);
        uint2 u2 = *(const uint2*)(ybase + (size_t)e1.x * CW + co);
        uint2 u3 = *(const uint2*)(ybase + (size_t)e1.z * CW + co);
        uint2 u4 = *(const uint2*)(ybase + (size_t)e2.x * CW + co);
        uint2 u5 = *(const uint2*)(ybase + (size_t)e2.z * CW + co);
        uint2 u6 = *(const uint2*)(ybase + (size_t)e3.x * CW + co);
        uint2 u7 = *(const uint2*)(ybase + (size_t)e3.z * CW + co);
        float w0 = __int_as_float(e0.y), w1 = __int_as_float(e0.w);
        float w2 = __int_as_float(e1.y), w3 = __int_as_float(e1.w);
        float w4 = __int_as_float(e2.y), w5 = __int_as_float(e2.w);
        float w6 = __int_as_float(e3.y), w7 = __int_as_float(e3.w);
        a0 = fmaf(w0, bf2f_lo(u0.x), a0); a1 = fmaf(w0, bf2f_hi(u0.x), a1);
        a2 = fmaf(w0, bf2f_lo(u0.y), a2); a3 = fmaf(w0, bf2f_hi(u0.y), a3);
        b0 = fmaf(w1, bf2f_lo(u1.x), b0); b1 = fmaf(w1, bf2f_hi(u1.x), b1);
        b2 = fmaf(w1, bf2f_lo(u1.y), b2); b3 = fmaf(w1, bf2f_hi(u1.y), b3);
        a0 = fmaf(w2, bf2f_lo(u2.x), a0); a1 = fmaf(w2, bf2f_hi(u2.x), a1);
        a2 = fmaf(w2, bf2f_lo(u2.y), a2); a3 = fmaf(w2, bf2f_hi(u2.y), a3);
        b0 = fmaf(w3, bf2f_lo(u3.x), b0); b1 = fmaf(w3, bf2f_hi(u3.x), b1);
        b2 = fmaf(w3, bf2f_lo(u3.y), b2); b3 = fmaf(w3, bf2f_hi(u3.y), b3);
        a0 = fmaf(w4, bf2f_lo(u4.x), a0); a1 = fmaf(w4, bf2f_hi(u4.x), a1);
        a2 = fmaf(w4, bf2f_lo(u4.y), a2); a3 = fmaf(w4, bf2f_hi(u4.y), a3);
        b0 = fmaf(w5, bf2f_lo(u5.x), b0); b1 = fmaf(w5, bf2f_hi(u5.x), b1);
        b2 = fmaf(w5, bf2f_lo(u5.y), b2); b3 = fmaf(w5, bf2f_hi(u5.y), b3);
        a0 = fmaf(w6, bf2f_lo(u6.x), a0); a1 = fmaf(w6, bf2f_hi(u6.x), a1);
        a2 = fmaf(w6, bf2f_lo(u6.y), a2); a3 = fmaf(w6, bf2f_hi(u6.y), a3);
        b0 = fmaf(w7, bf2f_lo(u7.x), b0); b1 = fmaf(w7, bf2f_hi(u7.x), b1);
        b2 = fmaf(w7, bf2f_lo(u7.y), b2); b3 = fmaf(w7, bf2f_hi(u7.y), b3);
    }
    for (; j < j1; j += 4) {
        int4 e0 = *(const int4*)(epk + j);
        int4 e1 = *(const int4*)(epk + j + 2);
        uint2 u0 = *(const uint2*)(ybase + (size_t)e0.x * CW + co);
        uint2 u1 = *(const uint2*)(ybase + (size_t)e0.z * CW + co);
        uint2 u2 = *(const uint2*)(ybase + (size_t)e1.x * CW + co);
        uint2 u3 = *(const uint2*)(ybase + (size_t)e1.z * CW + co);
        float w0 = __int_as_float(e0.y), w1 = __int_as_float(e0.w);
        float w2 = __int_as_float(e1.y), w3 = __int_as_float(e1.w);
        a0 = fmaf(w0, bf2f_lo(u0.x), a0); a1 = fmaf(w0, bf2f_hi(u0.x), a1);
        a2 = fmaf(w0, bf2f_lo(u0.y), a2); a3 = fmaf(w0, bf2f_hi(u0.y), a3);
        b0 = fmaf(w1, bf2f_lo(u1.x), b0); b1 = fmaf(w1, bf2f_hi(u1.x), b1);
        b2 = fmaf(w1, bf2f_lo(u1.y), b2); b3 = fmaf(w1, bf2f_hi(u1.y), b3);
        a0 = fmaf(w2, bf2f_lo(u2.x), a0); a1 = fmaf(w2, bf2f_hi(u2.x), a1);
        a2 = fmaf(w2, bf2f_lo(u2.y), a2); a3 = fmaf(w2, bf2f_hi(u2.y), a3);
        b0 = fmaf(w3, bf2f_lo(u3.x), b0); b1 = fmaf(w3, bf2f_hi(u3.x), b1);
        b2 = fmaf(w3, bf2f_lo(u3.y), b2); b3 = fmaf(w3, bf2f_hi(u3.y), b3);
    }
    float s0 = (a0 + b0) * INV_C, s1 = (a1 + b1) * INV_C;
    float s2 = (a2 + b2) * INV_C, s3 = (a3 + b3) * INV_C;
    if (FINAL) {
        uint2 pk;
        pk.x = (unsigned int)f2bf(s0) | ((unsigned int)f2bf(s1) << 16);
        pk.y = (unsigned int)f2bf(s2) | ((unsigned int)f2bf(s3) << 16);
        *(uint2*)(xibout + (size_t)row * DD + c * CW + co) = pk;
    } else {
        size_t o = (size_t)c * CHSZ + (size_t)row * CW + co;
        uint2 zv = *(const uint2*)(zb + o);
        s0 += bf2f_lo(zv.x); s1 += bf2f_hi(zv.x);
        s2 += bf2f_lo(zv.y); s3 += bf2f_hi(zv.y);
        uint2 pk;
        pk.x = (unsigned int)f2bf(s0) | ((unsigned int)f2bf(s1) << 16);
        pk.y = (unsigned int)f2bf(s2) | ((unsigned int)f2bf(s3) << 16);
        *(uint2*)(yout + o) = pk;
    }
}

// ---------------- BatchNorm stats over bf16 xi ----------------
__global__ __launch_bounds__(256) void bn_stats(const unsigned short* __restrict__ xib,
        float* __restrict__ sums) {
    const int cg = threadIdx.x & 15;    // 16 channel groups x 8 ch
    const int rs = threadIdx.x >> 4;    // 16 row slots
    float s[8], q[8];
    #pragma unroll
    for (int k = 0; k < 8; ++k) { s[k] = 0.f; q[k] = 0.f; }
    for (int r = blockIdx.x * 16 + rs; r < NSUP; r += gridDim.x * 16) {
        uint4 v = *(const uint4*)(xib + (size_t)r * DD + cg * 8);
        float f0 = bf2f_lo(v.x), f1 = bf2f_hi(v.x), f2 = bf2f_lo(v.y), f3 = bf2f_hi(v.y);
        float f4 = bf2f_lo(v.z), f5 = bf2f_hi(v.z), f6 = bf2f_lo(v.w), f7 = bf2f_hi(v.w);
        s[0] += f0; q[0] = fmaf(f0, f0, q[0]);
        s[1] += f1; q[1] = fmaf(f1, f1, q[1]);
        s[2] += f2; q[2] = fmaf(f2, f2, q[2]);
        s[3] += f3; q[3] = fmaf(f3, f3, q[3]);
        s[4] += f4; q[4] = fmaf(f4, f4, q[4]);
        s[5] += f5; q[5] = fmaf(f5, f5, q[5]);
        s[6] += f6; q[6] = fmaf(f6, f6, q[6]);
        s[7] += f7; q[7] = fmaf(f7, f7, q[7]);
    }
    __shared__ float ls[256][8];
    __shared__ float lq[256][8];
    #pragma unroll
    for (int k = 0; k < 8; ++k) { ls[threadIdx.x][k] = s[k]; lq[threadIdx.x][k] = q[k]; }
    __syncthreads();
    for (int off = 128; off >= 16; off >>= 1) {
        if (threadIdx.x < off) {
            #pragma unroll
            for (int k = 0; k < 8; ++k) {
                ls[threadIdx.x][k] += ls[threadIdx.x + off][k];
                lq[threadIdx.x][k] += lq[threadIdx.x + off][k];
            }
        }
        __syncthreads();
    }
    if (threadIdx.x < 16) {
        #pragma unroll
        for (int k = 0; k < 8; ++k) {
            atomicAdd(&sums[threadIdx.x * 8 + k], ls[threadIdx.x][k]);
            atomicAdd(&sums[128 + threadIdx.x * 8 + k], lq[threadIdx.x][k]);
        }
    }
}

// computes sc/sh, then zeroes stats for the next layer
__global__ void bn_finalize(float* __restrict__ sums, const float* __restrict__ gamma,
        const float* __restrict__ beta, float* __restrict__ sc) {
    int c = threadIdx.x;
    float mean = sums[c] * (1.0f / NSUP);
    float var = sums[128 + c] * (1.0f / NSUP) - mean * mean;
    float scale = gamma[c] / sqrtf(var + BN_EPS_C);
    sc[c] = scale;
    sc[128 + c] = beta[c] - mean * scale;
    __syncthreads();
    sums[c] = 0.f;
    sums[128 + c] = 0.f;
}

// final-layer BN apply: xib -> hb (bf16)
__global__ __launch_bounds__(256) void bn_apply(const unsigned short* __restrict__ xib,
        const float* __restrict__ scsh, unsigned short* __restrict__ hb) {
    int t = blockIdx.x * 256 + threadIdx.x;     // NSUP*16
    int r = t >> 4, g = t & 15;
    int col = g * 8;
    uint4 v = *(const uint4*)(xib + (size_t)r * DD + col);
    float4 sc0 = *(const float4*)(scsh + col), sc1 = *(const float4*)(scsh + col + 4);
    float4 sh0 = *(const float4*)(scsh + 128 + col), sh1 = *(const float4*)(scsh + 128 + col + 4);
    float f0 = lrelu(fmaf(bf2f_lo(v.x), sc0.x, sh0.x));
    float f1 = lrelu(fmaf(bf2f_hi(v.x), sc0.y, sh0.y));
    float f2 = lrelu(fmaf(bf2f_lo(v.y), sc0.z, sh0.z));
    float f3 = lrelu(fmaf(bf2f_hi(v.y), sc0.w, sh0.w));
    float f4 = lrelu(fmaf(bf2f_lo(v.z), sc1.x, sh1.x));
    float f5 = lrelu(fmaf(bf2f_hi(v.z), sc1.y, sh1.y));
    float f6 = lrelu(fmaf(bf2f_lo(v.w), sc1.z, sh1.z));
    float f7 = lrelu(fmaf(bf2f_hi(v.w), sc1.w, sh1.w));
    uint4 o;
    o.x = (unsigned int)f2bf(f0) | ((unsigned int)f2bf(f1) << 16);
    o.y = (unsigned int)f2bf(f2) | ((unsigned int)f2bf(f3) << 16);
    o.z = (unsigned int)f2bf(f4) | ((unsigned int)f2bf(f5) << 16);
    o.w = (unsigned int)f2bf(f6) | ((unsigned int)f2bf(f7) << 16);
    *(uint4*)(hb + (size_t)r * DD + col) = o;
}

// ---------------- unpool: hb (bf16) -> out (f32) ----------------
__global__ __launch_bounds__(256) void unpool(const unsigned short* __restrict__ hb,
        const int* __restrict__ seg, float* __restrict__ out) {
    int t = blockIdx.x * 256 + threadIdx.x;     // NPIX*16
    int p = t >> 4, g = t & 15;
    int s = seg[p];
    uint4 v = *(const uint4*)(hb + (size_t)s * DD + g * 8);
    float4 o0 = make_float4(bf2f_lo(v.x), bf2f_hi(v.x), bf2f_lo(v.y), bf2f_hi(v.y));
    float4 o1 = make_float4(bf2f_lo(v.z), bf2f_hi(v.z), bf2f_lo(v.w), bf2f_hi(v.w));
    *(float4*)(out + (size_t)p * DD + g * 8) = o0;
    *(float4*)(out + (size_t)p * DD + g * 8 + 4) = o1;
}

extern "C" void kernel_launch(void* const* d_in, const int* in_sizes, int n_in,
                              void* d_out, int out_size, void* d_ws, size_t ws_size,
                              hipStream_t stream) {
    const float* x     = (const float*)d_in[0];
    const float* W     = (const float*)d_in[1];
    const float* b     = (const float*)d_in[2];
    const float* gamma = (const float*)d_in[3];
    const float* beta  = (const float*)d_in[4];
    const float* ewt   = (const float*)d_in[5];
    const int*   seg   = (const int*)d_in[6];
    const int*   eidx  = (const int*)d_in[7];
    const int*   esrc  = eidx;
    const int*   edst  = eidx + NE;
    float* out = (float*)d_out;

    // d_out hosts transients (all bf16, dead before final unpool):
    //   xib 12.8MB | zb 12.8MB | ya 12.8MB | yb 12.8MB
    const size_t MAT = (size_t)NSUP * DD;
    unsigned short* xib = (unsigned short*)out;
    unsigned short* zb  = xib + MAT;
    unsigned short* ya  = zb + MAT;
    unsigned short* yb  = ya + MAT;

    char* ws = (char*)d_ws;
    size_t off = 0;
    auto alloc = [&](size_t bytes) -> void* {
        void* p = ws + off;
        off = (off + bytes + 255) & ~(size_t)255;
        return p;
    };
    unsigned short* hb  = (unsigned short*)alloc(sizeof(unsigned short) * MAT);  // 12.8 MB
    unsigned short* Wtb = (unsigned short*)alloc(sizeof(unsigned short) * NL * DD * DD);
    int*   rowcnt  = (int*)alloc(sizeof(int) * CNT_CAP);
    int*   rowptr  = (int*)alloc(sizeof(int) * (NSUP + 1));
    int*   rowfill = (int*)alloc(sizeof(int) * NSUP);
    int*   pixcnt  = (int*)alloc(sizeof(int) * CNT_CAP);
    int*   pixptr  = (int*)alloc(sizeof(int) * (NSUP + 1));
    int*   pixfill = (int*)alloc(sizeof(int) * NSUP);
    int*   pixids  = (int*)alloc(sizeof(int) * NPIX);
    int2*  epk     = (int2*)alloc(sizeof(int2) * NEPAD4);
    float* stats   = (float*)alloc(sizeof(float) * 256);
    float* sc      = (float*)alloc(sizeof(float) * 256);

    hipMemsetAsync(rowcnt, 0, sizeof(int) * CNT_CAP, stream);
    hipMemsetAsync(rowfill, 0, sizeof(int) * NSUP, stream);
    hipMemsetAsync(pixcnt, 0, sizeof(int) * CNT_CAP, stream);
    hipMemsetAsync(pixfill, 0, sizeof(int) * NSUP, stream);
    hipMemsetAsync(epk, 0, sizeof(int2) * NEPAD4, stream);     // pad -> (src 0, w 0.0)
    hipMemsetAsync(stats, 0, sizeof(float) * 256, stream);

    // W transpose+bf16 (all layers)
    wconv<<<(NL * DD * DD + 255) / 256, 256, 0, stream>>>(W, Wtb);

    // pixel CSR + pooling
    hist_k<<<(NPIX + 255) / 256, 256, 0, stream>>>(seg, pixcnt, NPIX);
    scan_rowptr<1><<<1, 1024, 0, stream>>>(pixcnt, pixptr);
    pix_scatter<<<(NPIX + 255) / 256, 256, 0, stream>>>(seg, pixptr, pixfill, pixids);
    pool_gather<<<NSUP / 8, 256, 0, stream>>>(x, pixptr, pixids, hb);

    // edge CSR by dst, rows padded to multiple of 4, interleaved (src,w)
    hist_k<<<(NE + 255) / 256, 256, 0, stream>>>(edst, rowcnt, NE);
    scan_rowptr<4><<<1, 1024, 0, stream>>>(rowcnt, rowptr);
    edge_scatter<<<(NE + 255) / 256, 256, 0, stream>>>(esrc, edst, ewt, rowptr, rowfill, epk);

    // 5 SFNet layers
    const dim3 sgrid(NSUP / 16, NCH);
    const int ggrid = (NSUP + 63) / 64;
    for (int i = 0; i < NL; ++i) {
        const unsigned short* aop = (i == 0) ? hb : xib;
        if (i == 0) {
            gemm_mfma<0><<<ggrid, 128, 0, stream>>>(aop, nullptr,
                    Wtb + (size_t)i * DD * DD, b + i * DD, zb);
            make_y0<0><<<NSUP * 16 / 256, 256, 0, stream>>>(aop, nullptr, zb, ya);
        } else {
            gemm_mfma<1><<<ggrid, 128, 0, stream>>>(aop, sc,
                    Wtb + (size_t)i * DD * DD, b + i * DD, zb);
            make_y0<1><<<NSUP * 16 / 256, 256, 0, stream>>>(aop, sc, zb, ya);
        }

        const unsigned short* ycur = ya;
        unsigned short* ynxt = yb;
        for (int t = 0; t < 4; ++t) {
            spmm_c<0><<<sgrid, 256, 0, stream>>>(ycur, rowptr, epk, zb, nullptr, ynxt);
            const unsigned short* tmp = ycur;
            ycur = ynxt;
            ynxt = (unsigned short*)tmp;
        }
        spmm_c<1><<<sgrid, 256, 0, stream>>>(ycur, rowptr, epk, nullptr, xib, nullptr);

        bn_stats<<<128, 256, 0, stream>>>(xib, stats);
        bn_finalize<<<1, 128, 0, stream>>>(stats, gamma + i * DD, beta + i * DD, sc);
    }

    // final: BN apply into hb (ws, bf16), then unpool (overwrites all of d_out)
    bn_apply<<<NSUP * 16 / 256, 256, 0, stream>>>(xib, sc, hb);
    unpool<<<NPIX * 16 / 256, 256, 0, stream>>>(hb, seg, out);
}

// Round 8
// 1259.604 us; speedup vs baseline: 1.2901x; 1.0468x over previous
//
#include <hip/hip_runtime.h>

#define NPIX 250000
#define NSUP 50000
#define NE   800000
#define DD   128
#define NL   5

#define BN_EPS_C 1e-5f
#define SLOPE 0.01f
#define INV_C (1.0f / 2.9f)

// edge capacity with per-row pad to multiple of 4
#define NEPAD4 (NE + 3 * NSUP)
#define SCAN_PER 52
#define CNT_CAP (1024 * SCAN_PER)

typedef __attribute__((ext_vector_type(8))) short short8v;   // 8 bf16 (4 VGPR)
typedef __attribute__((ext_vector_type(4))) float f32x4;     // MFMA acc

__device__ __forceinline__ size_t rowoff(int r) { return (size_t)r * DD; }

__device__ __forceinline__ unsigned short f2bf(float f) {
    unsigned int u = __float_as_uint(f);
    unsigned int r = (u + 0x7FFFu + ((u >> 16) & 1u)) >> 16;
    return (unsigned short)r;
}
__device__ __forceinline__ float bf2f_lo(unsigned int v) { return __uint_as_float(v << 16); }
__device__ __forceinline__ float bf2f_hi(unsigned int v) { return __uint_as_float(v & 0xFFFF0000u); }
__device__ __forceinline__ float lrelu(float o) { return o > 0.f ? o : SLOPE * o; }

// ---------------- generic histogram ----------------
__global__ __launch_bounds__(256) void hist_k(const int* __restrict__ ids,
        int* __restrict__ cnt, int n) {
    int e = blockIdx.x * 256 + threadIdx.x;
    if (e >= n) return;
    atomicAdd(cnt + ids[e], 1);
}

// ---------------- single-block scan over padded counters ----------------
template <int PAD>
__global__ __launch_bounds__(1024) void scan_rowptr(const int* __restrict__ cnt,
        int* __restrict__ rp) {
    const int t = threadIdx.x;
    const int lo = t * SCAN_PER;
    int4 c[SCAN_PER / 4];
    int s = 0;
    #pragma unroll
    for (int k = 0; k < SCAN_PER / 4; ++k) {
        int4 v = *(const int4*)(cnt + lo + k * 4);
        if (PAD > 1) {
            v.x = (v.x + PAD - 1) & ~(PAD - 1);
            v.y = (v.y + PAD - 1) & ~(PAD - 1);
            v.z = (v.z + PAD - 1) & ~(PAD - 1);
            v.w = (v.w + PAD - 1) & ~(PAD - 1);
        }
        c[k] = v;
        s += v.x + v.y + v.z + v.w;
    }
    int lane = t & 63, wid = t >> 6;
    int v = s;
    #pragma unroll
    for (int d = 1; d < 64; d <<= 1) {
        int u = __shfl_up(v, d);
        if (lane >= d) v += u;
    }
    __shared__ int wtot[16], woff[16];
    if (lane == 63) wtot[wid] = v;
    __syncthreads();
    if (t == 0) {
        int acc = 0;
        #pragma unroll
        for (int w = 0; w < 16; ++w) { woff[w] = acc; acc += wtot[w]; }
    }
    __syncthreads();
    int base = woff[wid] + v - s;
    #pragma unroll
    for (int k = 0; k < SCAN_PER / 4; ++k) {
        int i = lo + k * 4;
        if (i     <= NSUP) rp[i]     = base;  base += c[k].x;
        if (i + 1 <= NSUP) rp[i + 1] = base;  base += c[k].y;
        if (i + 2 <= NSUP) rp[i + 2] = base;  base += c[k].z;
        if (i + 3 <= NSUP) rp[i + 3] = base;  base += c[k].w;
    }
}

// ---------------- pixel scatter ----------------
__global__ __launch_bounds__(256) void pix_scatter(const int* __restrict__ seg,
        const int* __restrict__ rp, int* __restrict__ fill, int* __restrict__ pix) {
    int p = blockIdx.x * 256 + threadIdx.x;
    if (p >= NPIX) return;
    int s = seg[p];
    int pos = rp[s] + atomicAdd(fill + s, 1);
    pix[pos] = p;
}

// ---------------- edge scatter: interleaved (src, w) pairs ----------------
__global__ __launch_bounds__(256) void edge_scatter(const int* __restrict__ srcv,
        const int* __restrict__ dstv, const float* __restrict__ w,
        const int* __restrict__ rp, int* __restrict__ fill, int2* __restrict__ epk) {
    int e = blockIdx.x * 256 + threadIdx.x;
    if (e >= NE) return;
    int d = dstv[e];
    int pos = rp[d] + atomicAdd(fill + d, 1);
    epk[pos] = make_int2(srcv[e], __float_as_int(w[e]));
}

// ---------------- W transpose + bf16 convert: Wtb[l][n][k] = bf16(W[l][k][n]) ----------------
__global__ __launch_bounds__(256) void wconv(const float* __restrict__ W,
        unsigned short* __restrict__ Wtb) {
    int t = blockIdx.x * 256 + threadIdx.x;
    if (t >= NL * DD * DD) return;
    int l = t / (DD * DD);
    int rem = t - l * (DD * DD);
    int n = rem >> 7, k = rem & 127;
    Wtb[t] = f2bf(W[(size_t)l * DD * DD + (size_t)k * DD + n]);
}

// ---------------- pooling: half-wave per superpixel, 4-pixel unroll, bf16 out ----------------
__global__ __launch_bounds__(256) void pool_gather(const float* __restrict__ x,
        const int* __restrict__ pp, const int* __restrict__ pix, unsigned short* __restrict__ hb) {
    const int tid = threadIdx.x;
    const int wave = tid >> 6, lane = tid & 63;
    const int hf = lane >> 5, hl = lane & 31;
    const int row = blockIdx.x * 8 + wave * 2 + hf;
    const int j0 = pp[row], j1 = pp[row + 1];
    float4 a0 = make_float4(0.f, 0.f, 0.f, 0.f);
    float4 a1 = make_float4(0.f, 0.f, 0.f, 0.f);
    float4 a2 = make_float4(0.f, 0.f, 0.f, 0.f);
    float4 a3 = make_float4(0.f, 0.f, 0.f, 0.f);
    int j = j0;
    for (; j + 3 < j1; j += 4) {
        int p0 = pix[j], p1 = pix[j + 1], p2 = pix[j + 2], p3 = pix[j + 3];
        float4 v0 = *(const float4*)(x + rowoff(p0) + hl * 4);
        float4 v1 = *(const float4*)(x + rowoff(p1) + hl * 4);
        float4 v2 = *(const float4*)(x + rowoff(p2) + hl * 4);
        float4 v3 = *(const float4*)(x + rowoff(p3) + hl * 4);
        a0.x += v0.x; a0.y += v0.y; a0.z += v0.z; a0.w += v0.w;
        a1.x += v1.x; a1.y += v1.y; a1.z += v1.z; a1.w += v1.w;
        a2.x += v2.x; a2.y += v2.y; a2.z += v2.z; a2.w += v2.w;
        a3.x += v3.x; a3.y += v3.y; a3.z += v3.z; a3.w += v3.w;
    }
    for (; j < j1; ++j) {
        int p0 = pix[j];
        float4 v0 = *(const float4*)(x + rowoff(p0) + hl * 4);
        a0.x += v0.x; a0.y += v0.y; a0.z += v0.z; a0.w += v0.w;
    }
    float inv = 1.0f / fmaxf((float)(j1 - j0), 1.0f);
    float o0 = (a0.x + a1.x + a2.x + a3.x) * inv;
    float o1 = (a0.y + a1.y + a2.y + a3.y) * inv;
    float o2 = (a0.z + a1.z + a2.z + a3.z) * inv;
    float o3 = (a0.w + a1.w + a2.w + a3.w) * inv;
    uint2 pk;
    pk.x = (unsigned int)f2bf(o0) | ((unsigned int)f2bf(o1) << 16);
    pk.y = (unsigned int)f2bf(o2) | ((unsigned int)f2bf(o3) << 16);
    *(uint2*)(hb + rowoff(row) + hl * 4) = pk;
}

// ---------------- MFMA GEMM + fused y0 ----------------
// z = act(xib) @ W + b -> zb (row-major bf16); y0 = bf16(act(xib) + z) -> ya.
// act and z staged in LDS; phase 2 emits y0 coalesced.
// Wave: 32 rows x 128 cols; block 128 threads = 2 waves = 64 rows.
template <int FUSE>
__global__ __launch_bounds__(128) void gemm_mfma(const unsigned short* __restrict__ xib,
        const float* __restrict__ scsh, const unsigned short* __restrict__ Wtb,
        const float* __restrict__ bias, unsigned short* __restrict__ zb,
        unsigned short* __restrict__ y0) {
    __shared__ unsigned short act_s[64 * DD];   // 16 KB
    __shared__ unsigned short z_s[64 * DD];     // 16 KB
    const int wv = threadIdx.x >> 6;
    const int l  = threadIdx.x & 63;
    const int lr = l & 15;
    const int lk = (l >> 4) * 8;
    const int rbase = blockIdx.x * 64 + wv * 32;
    const int lbase = wv * 32;

    f32x4 acc[2][8];
    #pragma unroll
    for (int rt = 0; rt < 2; ++rt)
        #pragma unroll
        for (int nt = 0; nt < 8; ++nt)
            acc[rt][nt] = (f32x4){0.f, 0.f, 0.f, 0.f};

    #pragma unroll
    for (int kt = 0; kt < 4; ++kt) {
        const int kk = kt * 32 + lk;
        short8v bfr[8];
        #pragma unroll
        for (int nt = 0; nt < 8; ++nt)
            bfr[nt] = *(const short8v*)(Wtb + (size_t)(nt * 16 + lr) * DD + kk);
        float4 scv0, scv1, shv0, shv1;
        if (FUSE) {
            scv0 = *(const float4*)(scsh + kk);
            scv1 = *(const float4*)(scsh + kk + 4);
            shv0 = *(const float4*)(scsh + 128 + kk);
            shv1 = *(const float4*)(scsh + 128 + kk + 4);
        }
        #pragma unroll
        for (int rt = 0; rt < 2; ++rt) {
            int r = rbase + rt * 16 + lr;
            if (r >= NSUP) r = NSUP - 1;
            short8v a;
            if (FUSE) {
                uint4 av = *(const uint4*)(xib + (size_t)r * DD + kk);
                float f0 = lrelu(fmaf(bf2f_lo(av.x), scv0.x, shv0.x));
                float f1 = lrelu(fmaf(bf2f_hi(av.x), scv0.y, shv0.y));
                float f2 = lrelu(fmaf(bf2f_lo(av.y), scv0.z, shv0.z));
                float f3 = lrelu(fmaf(bf2f_hi(av.y), scv0.w, shv0.w));
                float f4 = lrelu(fmaf(bf2f_lo(av.z), scv1.x, shv1.x));
                float f5 = lrelu(fmaf(bf2f_hi(av.z), scv1.y, shv1.y));
                float f6 = lrelu(fmaf(bf2f_lo(av.w), scv1.z, shv1.z));
                float f7 = lrelu(fmaf(bf2f_hi(av.w), scv1.w, shv1.w));
                a[0] = (short)f2bf(f0); a[1] = (short)f2bf(f1);
                a[2] = (short)f2bf(f2); a[3] = (short)f2bf(f3);
                a[4] = (short)f2bf(f4); a[5] = (short)f2bf(f5);
                a[6] = (short)f2bf(f6); a[7] = (short)f2bf(f7);
            } else {
                a = *(const short8v*)(xib + (size_t)r * DD + kk);
            }
            *(short8v*)(act_s + (lbase + rt * 16 + lr) * DD + kk) = a;
            #pragma unroll
            for (int nt = 0; nt < 8; ++nt)
                acc[rt][nt] = __builtin_amdgcn_mfma_f32_16x16x32_bf16(a, bfr[nt], acc[rt][nt], 0, 0, 0);
        }
    }
    // epilogue: D layout col = l&15, row = (l>>4)*4 + j  [m89-verified]
    #pragma unroll
    for (int rt = 0; rt < 2; ++rt) {
        const int orow = rbase + rt * 16 + (l >> 4) * 4;
        const int lrow = lbase + rt * 16 + (l >> 4) * 4;
        #pragma unroll
        for (int nt = 0; nt < 8; ++nt) {
            const int col = nt * 16 + lr;
            const float bs = bias[col];
            #pragma unroll
            for (int j = 0; j < 4; ++j) {
                unsigned short zv = f2bf(acc[rt][nt][j] + bs);
                z_s[(lrow + j) * DD + col] = zv;
                int r = orow + j;
                if (r < NSUP)
                    zb[(size_t)r * DD + col] = zv;
            }
        }
    }
    __syncthreads();
    // phase 2: y0 = act + z, coalesced
    for (int i = threadIdx.x; i < 64 * 16; i += 128) {
        int lrow = i >> 4, g = i & 15;
        int r = blockIdx.x * 64 + lrow;
        if (r >= NSUP) continue;
        uint4 av = *(const uint4*)(act_s + lrow * DD + g * 8);
        uint4 zv = *(const uint4*)(z_s + lrow * DD + g * 8);
        float f0 = bf2f_lo(av.x) + bf2f_lo(zv.x), f1 = bf2f_hi(av.x) + bf2f_hi(zv.x);
        float f2 = bf2f_lo(av.y) + bf2f_lo(zv.y), f3 = bf2f_hi(av.y) + bf2f_hi(zv.y);
        float f4 = bf2f_lo(av.z) + bf2f_lo(zv.z), f5 = bf2f_hi(av.z) + bf2f_hi(zv.z);
        float f6 = bf2f_lo(av.w) + bf2f_lo(zv.w), f7 = bf2f_hi(av.w) + bf2f_hi(zv.w);
        uint4 o;
        o.x = (unsigned int)f2bf(f0) | ((unsigned int)f2bf(f1) << 16);
        o.y = (unsigned int)f2bf(f2) | ((unsigned int)f2bf(f3) << 16);
        o.z = (unsigned int)f2bf(f4) | ((unsigned int)f2bf(f5) << 16);
        o.w = (unsigned int)f2bf(f6) | ((unsigned int)f2bf(f7) << 16);
        *(uint4*)(y0 + (size_t)r * DD + g * 8) = o;
    }
}

// ---------------- SpMM: full 256B row, quarter-wave per row, 8-deep gather ILP ----------
// FINAL=0: yout = bf16( (A@y)*INV_C + zb )
// FINAL=1: xibout = bf16( (A@y)*INV_C )
template <int FINAL>
__global__ __launch_bounds__(256) void spmm_q(const unsigned short* __restrict__ yin,
        const int* __restrict__ rp, const int2* __restrict__ epk,
        const unsigned short* __restrict__ zb, unsigned short* __restrict__ xibout,
        unsigned short* __restrict__ yout) {
    const int tid = threadIdx.x;
    const int wave = tid >> 6, lane = tid & 63;
    const int q = lane >> 4, ql = lane & 15;
    const int row = blockIdx.x * 16 + wave * 4 + q;
    const int j0 = rp[row], j1 = rp[row + 1];
    const size_t fo = (size_t)ql * 8;           // 8 bf16 = 16B per lane
    float a0 = 0.f, a1 = 0.f, a2 = 0.f, a3 = 0.f;
    float a4 = 0.f, a5 = 0.f, a6 = 0.f, a7 = 0.f;
    float b0 = 0.f, b1 = 0.f, b2 = 0.f, b3 = 0.f;
    float b4 = 0.f, b5 = 0.f, b6 = 0.f, b7 = 0.f;
    int j = j0;
    #define EDGE_FMA(ACC0,ACC1,ACC2,ACC3,ACC4,ACC5,ACC6,ACC7,U,W) \
        ACC0 = fmaf(W, bf2f_lo(U.x), ACC0); ACC1 = fmaf(W, bf2f_hi(U.x), ACC1); \
        ACC2 = fmaf(W, bf2f_lo(U.y), ACC2); ACC3 = fmaf(W, bf2f_hi(U.y), ACC3); \
        ACC4 = fmaf(W, bf2f_lo(U.z), ACC4); ACC5 = fmaf(W, bf2f_hi(U.z), ACC5); \
        ACC6 = fmaf(W, bf2f_lo(U.w), ACC6); ACC7 = fmaf(W, bf2f_hi(U.w), ACC7);
    for (; j + 8 <= j1; j += 8) {
        int4 e0 = *(const int4*)(epk + j);
        int4 e1 = *(const int4*)(epk + j + 2);
        int4 e2 = *(const int4*)(epk + j + 4);
        int4 e3 = *(const int4*)(epk + j + 6);
        uint4 u0 = *(const uint4*)(yin + rowoff(e0.x) + fo);
        uint4 u1 = *(const uint4*)(yin + rowoff(e0.z) + fo);
        uint4 u2 = *(const uint4*)(yin + rowoff(e1.x) + fo);
        uint4 u3 = *(const uint4*)(yin + rowoff(e1.z) + fo);
        uint4 u4 = *(const uint4*)(yin + rowoff(e2.x) + fo);
        uint4 u5 = *(const uint4*)(yin + rowoff(e2.z) + fo);
        uint4 u6 = *(const uint4*)(yin + rowoff(e3.x) + fo);
        uint4 u7 = *(const uint4*)(yin + rowoff(e3.z) + fo);
        float w0 = __int_as_float(e0.y), w1 = __int_as_float(e0.w);
        float w2 = __int_as_float(e1.y), w3 = __int_as_float(e1.w);
        float w4 = __int_as_float(e2.y), w5 = __int_as_float(e2.w);
        float w6 = __int_as_float(e3.y), w7 = __int_as_float(e3.w);
        EDGE_FMA(a0,a1,a2,a3,a4,a5,a6,a7, u0, w0)
        EDGE_FMA(b0,b1,b2,b3,b4,b5,b6,b7, u1, w1)
        EDGE_FMA(a0,a1,a2,a3,a4,a5,a6,a7, u2, w2)
        EDGE_FMA(b0,b1,b2,b3,b4,b5,b6,b7, u3, w3)
        EDGE_FMA(a0,a1,a2,a3,a4,a5,a6,a7, u4, w4)
        EDGE_FMA(b0,b1,b2,b3,b4,b5,b6,b7, u5, w5)
        EDGE_FMA(a0,a1,a2,a3,a4,a5,a6,a7, u6, w6)
        EDGE_FMA(b0,b1,b2,b3,b4,b5,b6,b7, u7, w7)
    }
    for (; j < j1; j += 4) {
        int4 e0 = *(const int4*)(epk + j);
        int4 e1 = *(const int4*)(epk + j + 2);
        uint4 u0 = *(const uint4*)(yin + rowoff(e0.x) + fo);
        uint4 u1 = *(const uint4*)(yin + rowoff(e0.z) + fo);
        uint4 u2 = *(const uint4*)(yin + rowoff(e1.x) + fo);
        uint4 u3 = *(const uint4*)(yin + rowoff(e1.z) + fo);
        float w0 = __int_as_float(e0.y), w1 = __int_as_float(e0.w);
        float w2 = __int_as_float(e1.y), w3 = __int_as_float(e1.w);
        EDGE_FMA(a0,a1,a2,a3,a4,a5,a6,a7, u0, w0)
        EDGE_FMA(b0,b1,b2,b3,b4,b5,b6,b7, u1, w1)
        EDGE_FMA(a0,a1,a2,a3,a4,a5,a6,a7, u2, w2)
        EDGE_FMA(b0,b1,b2,b3,b4,b5,b6,b7, u3, w3)
    }
    #undef EDGE_FMA
    float s0 = (a0 + b0) * INV_C, s1 = (a1 + b1) * INV_C;
    float s2 = (a2 + b2) * INV_C, s3 = (a3 + b3) * INV_C;
    float s4 = (a4 + b4) * INV_C, s5 = (a5 + b5) * INV_C;
    float s6 = (a6 + b6) * INV_C, s7 = (a7 + b7) * INV_C;
    if (!FINAL) {
        uint4 zv = *(const uint4*)(zb + rowoff(row) + fo);
        s0 += bf2f_lo(zv.x); s1 += bf2f_hi(zv.x);
        s2 += bf2f_lo(zv.y); s3 += bf2f_hi(zv.y);
        s4 += bf2f_lo(zv.z); s5 += bf2f_hi(zv.z);
        s6 += bf2f_lo(zv.w); s7 += bf2f_hi(zv.w);
    }
    uint4 o;
    o.x = (unsigned int)f2bf(s0) | ((unsigned int)f2bf(s1) << 16);
    o.y = (unsigned int)f2bf(s2) | ((unsigned int)f2bf(s3) << 16);
    o.z = (unsigned int)f2bf(s4) | ((unsigned int)f2bf(s5) << 16);
    o.w = (unsigned int)f2bf(s6) | ((unsigned int)f2bf(s7) << 16);
    if (FINAL)
        *(uint4*)(xibout + rowoff(row) + fo) = o;
    else
        *(uint4*)(yout + rowoff(row) + fo) = o;
}

// ---------------- BatchNorm stats over bf16 xi ----------------
__global__ __launch_bounds__(256) void bn_stats(const unsigned short* __restrict__ xib,
        float* __restrict__ sums) {
    const int cg = threadIdx.x & 15;
    const int rs = threadIdx.x >> 4;
    float s[8], q[8];
    #pragma unroll
    for (int k = 0; k < 8; ++k) { s[k] = 0.f; q[k] = 0.f; }
    for (int r = blockIdx.x * 16 + rs; r < NSUP; r += gridDim.x * 16) {
        uint4 v = *(const uint4*)(xib + (size_t)r * DD + cg * 8);
        float f0 = bf2f_lo(v.x), f1 = bf2f_hi(v.x), f2 = bf2f_lo(v.y), f3 = bf2f_hi(v.y);
        float f4 = bf2f_lo(v.z), f5 = bf2f_hi(v.z), f6 = bf2f_lo(v.w), f7 = bf2f_hi(v.w);
        s[0] += f0; q[0] = fmaf(f0, f0, q[0]);
        s[1] += f1; q[1] = fmaf(f1, f1, q[1]);
        s[2] += f2; q[2] = fmaf(f2, f2, q[2]);
        s[3] += f3; q[3] = fmaf(f3, f3, q[3]);
        s[4] += f4; q[4] = fmaf(f4, f4, q[4]);
        s[5] += f5; q[5] = fmaf(f5, f5, q[5]);
        s[6] += f6; q[6] = fmaf(f6, f6, q[6]);
        s[7] += f7; q[7] = fmaf(f7, f7, q[7]);
    }
    __shared__ float ls[256][8];
    __shared__ float lq[256][8];
    #pragma unroll
    for (int k = 0; k < 8; ++k) { ls[threadIdx.x][k] = s[k]; lq[threadIdx.x][k] = q[k]; }
    __syncthreads();
    for (int off = 128; off >= 16; off >>= 1) {
        if (threadIdx.x < off) {
            #pragma unroll
            for (int k = 0; k < 8; ++k) {
                ls[threadIdx.x][k] += ls[threadIdx.x + off][k];
                lq[threadIdx.x][k] += lq[threadIdx.x + off][k];
            }
        }
        __syncthreads();
    }
    if (threadIdx.x < 16) {
        #pragma unroll
        for (int k = 0; k < 8; ++k) {
            atomicAdd(&sums[threadIdx.x * 8 + k], ls[threadIdx.x][k]);
            atomicAdd(&sums[128 + threadIdx.x * 8 + k], lq[threadIdx.x][k]);
        }
    }
}

// computes sc/sh, then zeroes stats for the next layer
__global__ void bn_finalize(float* __restrict__ sums, const float* __restrict__ gamma,
        const float* __restrict__ beta, float* __restrict__ sc) {
    int c = threadIdx.x;
    float mean = sums[c] * (1.0f / NSUP);
    float var = sums[128 + c] * (1.0f / NSUP) - mean * mean;
    float scale = gamma[c] / sqrtf(var + BN_EPS_C);
    sc[c] = scale;
    sc[128 + c] = beta[c] - mean * scale;
    __syncthreads();
    sums[c] = 0.f;
    sums[128 + c] = 0.f;
}

// ---------------- unpool with fused final BN+leaky: xib (ws) -> out (f32) ----------------
__global__ __launch_bounds__(256) void unpool_bn(const unsigned short* __restrict__ xib,
        const float* __restrict__ scsh, const int* __restrict__ seg, float* __restrict__ out) {
    int t = blockIdx.x * 256 + threadIdx.x;     // NPIX*16
    int p = t >> 4, g = t & 15;
    int s = seg[p];
    int col = g * 8;
    uint4 v = *(const uint4*)(xib + (size_t)s * DD + col);
    float4 sc0 = *(const float4*)(scsh + col), sc1 = *(const float4*)(scsh + col + 4);
    float4 sh0 = *(const float4*)(scsh + 128 + col), sh1 = *(const float4*)(scsh + 128 + col + 4);
    float4 o0, o1;
    o0.x = lrelu(fmaf(bf2f_lo(v.x), sc0.x, sh0.x));
    o0.y = lrelu(fmaf(bf2f_hi(v.x), sc0.y, sh0.y));
    o0.z = lrelu(fmaf(bf2f_lo(v.y), sc0.z, sh0.z));
    o0.w = lrelu(fmaf(bf2f_hi(v.y), sc0.w, sh0.w));
    o1.x = lrelu(fmaf(bf2f_lo(v.z), sc1.x, sh1.x));
    o1.y = lrelu(fmaf(bf2f_hi(v.z), sc1.y, sh1.y));
    o1.z = lrelu(fmaf(bf2f_lo(v.w), sc1.z, sh1.z));
    o1.w = lrelu(fmaf(bf2f_hi(v.w), sc1.w, sh1.w));
    *(float4*)(out + (size_t)p * DD + col) = o0;
    *(float4*)(out + (size_t)p * DD + col + 4) = o1;
}

extern "C" void kernel_launch(void* const* d_in, const int* in_sizes, int n_in,
                              void* d_out, int out_size, void* d_ws, size_t ws_size,
                              hipStream_t stream) {
    const float* x     = (const float*)d_in[0];
    const float* W     = (const float*)d_in[1];
    const float* b     = (const float*)d_in[2];
    const float* gamma = (const float*)d_in[3];
    const float* beta  = (const float*)d_in[4];
    const float* ewt   = (const float*)d_in[5];
    const int*   seg   = (const int*)d_in[6];
    const int*   eidx  = (const int*)d_in[7];
    const int*   esrc  = eidx;
    const int*   edst  = eidx + NE;
    float* out = (float*)d_out;

    // d_out hosts transients zb | ya | yb (bf16 row-major, 38.4MB), dead before unpool.
    // xib lives in ws so the final unpool can read it while writing all of d_out.
    const size_t MAT = (size_t)NSUP * DD;
    unsigned short* zb = (unsigned short*)out;
    unsigned short* ya = zb + MAT;
    unsigned short* yb = ya + MAT;

    char* ws = (char*)d_ws;
    size_t off = 0;
    auto alloc = [&](size_t bytes) -> void* {
        void* p = ws + off;
        off = (off + bytes + 255) & ~(size_t)255;
        return p;
    };
    unsigned short* xib = (unsigned short*)alloc(sizeof(unsigned short) * MAT);  // 12.8 MB
    unsigned short* hb  = (unsigned short*)alloc(sizeof(unsigned short) * MAT);  // 12.8 MB
    unsigned short* Wtb = (unsigned short*)alloc(sizeof(unsigned short) * NL * DD * DD);
    int*   rowcnt  = (int*)alloc(sizeof(int) * CNT_CAP);
    int*   rowptr  = (int*)alloc(sizeof(int) * (NSUP + 1));
    int*   rowfill = (int*)alloc(sizeof(int) * NSUP);
    int*   pixcnt  = (int*)alloc(sizeof(int) * CNT_CAP);
    int*   pixptr  = (int*)alloc(sizeof(int) * (NSUP + 1));
    int*   pixfill = (int*)alloc(sizeof(int) * NSUP);
    int*   pixids  = (int*)alloc(sizeof(int) * NPIX);
    int2*  epk     = (int2*)alloc(sizeof(int2) * NEPAD4);
    float* stats   = (float*)alloc(sizeof(float) * 256);
    float* sc      = (float*)alloc(sizeof(float) * 256);

    hipMemsetAsync(rowcnt, 0, sizeof(int) * CNT_CAP, stream);
    hipMemsetAsync(rowfill, 0, sizeof(int) * NSUP, stream);
    hipMemsetAsync(pixcnt, 0, sizeof(int) * CNT_CAP, stream);
    hipMemsetAsync(pixfill, 0, sizeof(int) * NSUP, stream);
    hipMemsetAsync(epk, 0, sizeof(int2) * NEPAD4, stream);     // pad -> (src 0, w 0.0)
    hipMemsetAsync(stats, 0, sizeof(float) * 256, stream);

    // W transpose+bf16 (all layers)
    wconv<<<(NL * DD * DD + 255) / 256, 256, 0, stream>>>(W, Wtb);

    // pixel CSR + pooling
    hist_k<<<(NPIX + 255) / 256, 256, 0, stream>>>(seg, pixcnt, NPIX);
    scan_rowptr<1><<<1, 1024, 0, stream>>>(pixcnt, pixptr);
    pix_scatter<<<(NPIX + 255) / 256, 256, 0, stream>>>(seg, pixptr, pixfill, pixids);
    pool_gather<<<NSUP / 8, 256, 0, stream>>>(x, pixptr, pixids, hb);

    // edge CSR by dst, rows padded to multiple of 4, interleaved (src,w)
    hist_k<<<(NE + 255) / 256, 256, 0, stream>>>(edst, rowcnt, NE);
    scan_rowptr<4><<<1, 1024, 0, stream>>>(rowcnt, rowptr);
    edge_scatter<<<(NE + 255) / 256, 256, 0, stream>>>(esrc, edst, ewt, rowptr, rowfill, epk);

    // 5 SFNet layers
    const int ggrid = (NSUP + 63) / 64;
    for (int i = 0; i < NL; ++i) {
        const unsigned short* aop = (i == 0) ? hb : xib;
        if (i == 0)
            gemm_mfma<0><<<ggrid, 128, 0, stream>>>(aop, nullptr,
                    Wtb + (size_t)i * DD * DD, b + i * DD, zb, ya);
        else
            gemm_mfma<1><<<ggrid, 128, 0, stream>>>(aop, sc,
                    Wtb + (size_t)i * DD * DD, b + i * DD, zb, ya);

        const unsigned short* ycur = ya;
        unsigned short* ynxt = yb;
        for (int t = 0; t < 4; ++t) {
            spmm_q<0><<<NSUP / 16, 256, 0, stream>>>(ycur, rowptr, epk, zb, nullptr, ynxt);
            const unsigned short* tmp = ycur;
            ycur = ynxt;
            ynxt = (unsigned short*)tmp;
        }
        spmm_q<1><<<NSUP / 16, 256, 0, stream>>>(ycur, rowptr, epk, nullptr, xib, nullptr);

        bn_stats<<<128, 256, 0, stream>>>(xib, stats);
        bn_finalize<<<1, 128, 0, stream>>>(stats, gamma + i * DD, beta + i * DD, sc);
    }

    // final: BN+leaky fused into unpool (overwrites all of d_out)
    unpool_bn<<<NPIX * 16 / 256, 256, 0, stream>>>(xib, sc, seg, out);
}